// Round 1
// baseline (906.144 us; speedup 1.0000x reference)
//
#include <hip/hip_runtime.h>

#define B_ 2
#define S_ 1024
#define D_ 2048
#define H_ 32
#define KV_ 4
#define HD_ 64
#define NQKV 2560  // H*HD + KV*HD + KV*HD

typedef __attribute__((ext_vector_type(8))) short bf16x8;
typedef __attribute__((ext_vector_type(4))) float f32x4;

__device__ __forceinline__ unsigned short f2bf(float f) {
  unsigned int u = __float_as_uint(f);
  u = (u + 0x7fffu + ((u >> 16) & 1u)) >> 16;   // RNE
  return (unsigned short)u;
}
__device__ __forceinline__ float bflo(unsigned int w) { return __uint_as_float(w << 16); }
__device__ __forceinline__ float bfhi(unsigned int w) { return __uint_as_float(w & 0xffff0000u); }

// ---------------- elementwise f32 -> bf16 ----------------
__global__ __launch_bounds__(256) void k_convert(const float* __restrict__ src,
                                                 unsigned short* __restrict__ dst, int n4) {
  int i = blockIdx.x * 256 + threadIdx.x;
  if (i >= n4) return;
  float4 v = ((const float4*)src)[i];
  ushort4 o;
  o.x = f2bf(v.x); o.y = f2bf(v.y); o.z = f2bf(v.z); o.w = f2bf(v.w);
  ((ushort4*)dst)[i] = o;
}

// ---------------- transpose f32 (K x N) -> bf16 (N x K), row offset into dst ----------------
__global__ __launch_bounds__(256) void k_transpose(const float* __restrict__ src,
                                                   unsigned short* __restrict__ dst,
                                                   int K, int N, int roff, int dld) {
  __shared__ float tile[32][33];
  int n0 = blockIdx.x * 32, k0 = blockIdx.y * 32;
  int tx = threadIdx.x & 31, ty = threadIdx.x >> 5;  // ty 0..7
  #pragma unroll
  for (int i = 0; i < 4; ++i)
    tile[ty + 8 * i][tx] = src[(size_t)(k0 + ty + 8 * i) * N + (n0 + tx)];
  __syncthreads();
  #pragma unroll
  for (int i = 0; i < 4; ++i)
    dst[(size_t)(roff + n0 + ty + 8 * i) * dld + (k0 + tx)] = f2bf(tile[tx][ty + 8 * i]);
}

// ---------------- GEMM: C[M][N] = A[M][K] * Bt[N][K]^T, bf16 in, f32 out ----------------
// 128x128 tile, BK=64, 4 waves (2x2 of 64x64), mfma_f32_16x16x32_bf16 (m97 structure)
__global__ __launch_bounds__(256) void k_gemm_bt(const unsigned short* __restrict__ A,
                                                 const unsigned short* __restrict__ Bt,
                                                 float* __restrict__ C, int M, int N, int K) {
  __shared__ alignas(16) unsigned short As[128 * 64];
  __shared__ alignas(16) unsigned short Bs[128 * 64];
  const int tid = threadIdx.x;
  const int wid = tid >> 6, lane = tid & 63;
  const int m0 = blockIdx.y * 128, n0 = blockIdx.x * 128;
  const int wr = wid >> 1, wc = wid & 1;
  f32x4 acc[4][4] = {};

  const int nkt = K >> 6;
  for (int kt = 0; kt < nkt; ++kt) {
    __syncthreads();
    #pragma unroll
    for (int i = 0; i < 4; ++i) {
      int o = (wid * 4 + i) * 512 + lane * 8;  // halfword offset in tile (wave-uniform base + lane*16B)
      int row = o >> 6;                        // 64 halfwords per row
      int kc = o & 63;
      const unsigned short* ga = A + (size_t)(m0 + row) * K + kt * 64 + kc;
      __builtin_amdgcn_global_load_lds((const __attribute__((address_space(1))) void*)ga,
                                       (__attribute__((address_space(3))) void*)(As + o), 16, 0, 0);
      const unsigned short* gb = Bt + (size_t)(n0 + row) * K + kt * 64 + kc;
      __builtin_amdgcn_global_load_lds((const __attribute__((address_space(1))) void*)gb,
                                       (__attribute__((address_space(3))) void*)(Bs + o), 16, 0, 0);
    }
    __syncthreads();
    #pragma unroll
    for (int ks = 0; ks < 2; ++ks) {
      bf16x8 a[4], b[4];
      #pragma unroll
      for (int m = 0; m < 4; ++m) {
        int row = wr * 64 + m * 16 + (lane & 15);
        int col = ks * 32 + ((lane >> 4) * 8);
        a[m] = *(const bf16x8*)(As + row * 64 + col);
      }
      #pragma unroll
      for (int n = 0; n < 4; ++n) {
        int row = wc * 64 + n * 16 + (lane & 15);
        int col = ks * 32 + ((lane >> 4) * 8);
        b[n] = *(const bf16x8*)(Bs + row * 64 + col);
      }
      #pragma unroll
      for (int m = 0; m < 4; ++m)
        #pragma unroll
        for (int n = 0; n < 4; ++n)
          acc[m][n] = __builtin_amdgcn_mfma_f32_16x16x32_bf16(a[m], b[n], acc[m][n], 0, 0, 0);
    }
  }
  const int cr = (lane >> 4) * 4;
  const int cc = lane & 15;
  #pragma unroll
  for (int m = 0; m < 4; ++m)
    #pragma unroll
    for (int n = 0; n < 4; ++n) {
      int col = n0 + wc * 64 + n * 16 + cc;
      int rowb = m0 + wr * 64 + m * 16 + cr;
      #pragma unroll
      for (int r = 0; r < 4; ++r)
        C[(size_t)(rowb + r) * N + col] = acc[m][n][r];
    }
}

// ---------------- RoPE q: qkv f32 -> q_r bf16 (B,H,S,HD) ----------------
__global__ __launch_bounds__(256) void k_rope_q(const float* __restrict__ qkv,
                                                const float* __restrict__ cosT,
                                                const float* __restrict__ sinT,
                                                const int* __restrict__ posp,
                                                unsigned short* __restrict__ q_r) {
  int t = blockIdx.x * 256 + threadIdx.x;
  int i = t & 31, h = (t >> 5) & 31, s = (t >> 10) & 1023, b = t >> 20;
  int pos = posp[0];
  const float* row = qkv + (size_t)(b * S_ + s) * NQKV + h * HD_;
  float q1 = row[i], q2 = row[i + 32];
  float c = cosT[(pos + s) * 32 + i], sn = sinT[(pos + s) * 32 + i];
  size_t o = ((size_t)(b * H_ + h) * S_ + s) * HD_ + i;
  q_r[o] = f2bf(q1 * c - q2 * sn);
  q_r[o + 32] = f2bf(q2 * c + q1 * sn);
}

// ---------------- RoPE k: qkv f32 -> k_r bf16 (B,KV,S,HD) ----------------
__global__ __launch_bounds__(256) void k_rope_k(const float* __restrict__ qkv,
                                                const float* __restrict__ cosT,
                                                const float* __restrict__ sinT,
                                                const int* __restrict__ posp,
                                                unsigned short* __restrict__ k_r) {
  int t = blockIdx.x * 256 + threadIdx.x;
  int i = t & 31, g = (t >> 5) & 3, s = (t >> 7) & 1023, b = t >> 17;
  int pos = posp[0];
  const float* row = qkv + (size_t)(b * S_ + s) * NQKV + 2048 + g * HD_;
  float k1 = row[i], k2 = row[i + 32];
  float c = cosT[(pos + s) * 32 + i], sn = sinT[(pos + s) * 32 + i];
  size_t o = ((size_t)(b * KV_ + g) * S_ + s) * HD_ + i;
  k_r[o] = f2bf(k1 * c - k2 * sn);
  k_r[o + 32] = f2bf(k2 * c + k1 * sn);
}

// ---------------- v: qkv f32 -> v_c bf16 (B,KV,S,HD) ----------------
__global__ __launch_bounds__(256) void k_conv_v(const float* __restrict__ qkv,
                                                unsigned short* __restrict__ v_c) {
  int t = blockIdx.x * 256 + threadIdx.x;
  int d = t & 63, g = (t >> 6) & 3, s = (t >> 8) & 1023, b = t >> 18;
  float v = qkv[(size_t)(b * S_ + s) * NQKV + 2304 + g * HD_ + d];
  v_c[((size_t)(b * KV_ + g) * S_ + s) * HD_ + d] = f2bf(v);
}

// ---------------- causal flash attention: 4 waves/block, 1 q-row/wave ----------------
__global__ __launch_bounds__(256) void k_attn(const unsigned short* __restrict__ qr,
                                              const unsigned short* __restrict__ kr,
                                              const unsigned short* __restrict__ vc,
                                              unsigned short* __restrict__ ao) {
  __shared__ alignas(16) unsigned short k_lds[64 * 64];  // XOR-swizzled rows
  __shared__ alignas(16) unsigned short v_lds[64 * 64];  // plain row-major
  const int wid = threadIdx.x >> 6, lane = threadIdx.x & 63;
  const int b = blockIdx.z, h = blockIdx.y, g = h >> 3;
  const int s_q = blockIdx.x * 4 + wid;

  // q row held per-lane (all lanes same row) as packed bf16
  const uint4* qp = (const uint4*)(qr + (((size_t)(b * H_ + h) * S_) + s_q) * HD_);
  uint4 qv[8];
  #pragma unroll
  for (int i = 0; i < 8; ++i) qv[i] = qp[i];

  float oacc = 0.f, mrun = -1e30f, lrun = 0.f;
  const unsigned short* kbase = kr + ((size_t)(b * KV_ + g) * S_) * HD_;
  const unsigned short* vbase = vc + ((size_t)(b * KV_ + g) * S_) * HD_;
  const int nch = (blockIdx.x * 4 + 3) / 64 + 1;  // same for all 4 waves (rows 4-aligned)

  for (int c = 0; c < nch; ++c) {
    const int j0 = c * 64;
    __syncthreads();
    // cooperative stage of K (swizzled) and V chunk: 64x64 bf16 each
    #pragma unroll
    for (int i = 0; i < 2; ++i) {
      int idx = threadIdx.x * 2 + i;  // 0..511
      int j = idx >> 3, d16 = idx & 7;
      uint4 kk = *(const uint4*)(kbase + (size_t)(j0 + j) * HD_ + d16 * 8);
      *(uint4*)((char*)k_lds + (j * 128 + ((d16 * 16) ^ ((j & 7) << 4)))) = kk;
      uint4 vv = *(const uint4*)(vbase + (size_t)(j0 + j) * HD_ + d16 * 8);
      *(uint4*)((char*)v_lds + (j * 128 + d16 * 16)) = vv;
    }
    __syncthreads();

    // scores: lane = k position j0+lane
    float sc = 0.f;
    #pragma unroll
    for (int d16 = 0; d16 < 8; ++d16) {
      uint4 kk = *(const uint4*)((const char*)k_lds + (lane * 128 + ((d16 * 16) ^ ((lane & 7) << 4))));
      uint4 qq = qv[d16];
      sc = fmaf(bflo(kk.x), bflo(qq.x), sc); sc = fmaf(bfhi(kk.x), bfhi(qq.x), sc);
      sc = fmaf(bflo(kk.y), bflo(qq.y), sc); sc = fmaf(bfhi(kk.y), bfhi(qq.y), sc);
      sc = fmaf(bflo(kk.z), bflo(qq.z), sc); sc = fmaf(bfhi(kk.z), bfhi(qq.z), sc);
      sc = fmaf(bflo(kk.w), bflo(qq.w), sc); sc = fmaf(bfhi(kk.w), bfhi(qq.w), sc);
    }
    sc *= 0.125f;  // 1/sqrt(64)
    if (j0 + lane > s_q) sc = -1e30f;  // causal mask

    // online softmax (wave reduce)
    float cm = sc;
    #pragma unroll
    for (int off = 32; off > 0; off >>= 1) cm = fmaxf(cm, __shfl_xor(cm, off, 64));
    float mn = fmaxf(mrun, cm);
    float scale = __expf(mrun - mn);
    float p = __expf(sc - mn);
    float ps = p;
    #pragma unroll
    for (int off = 32; off > 0; off >>= 1) ps += __shfl_xor(ps, off, 64);
    lrun = lrun * scale + ps;
    oacc *= scale;
    mrun = mn;

    // PV: lane owns output dim d=lane
    int jmax = s_q - j0 + 1;
    if (jmax > 64) jmax = 64;
    for (int jj = 0; jj < jmax; ++jj) {
      float pj = __shfl(p, jj, 64);
      unsigned short vw = *(const unsigned short*)((const char*)v_lds + (jj * 128 + lane * 2));
      oacc = fmaf(pj, __uint_as_float(((unsigned int)vw) << 16), oacc);
    }
  }
  float inv = 1.f / lrun;
  ao[((size_t)(b * S_ + s_q) * (H_ * HD_)) + h * HD_ + lane] = f2bf(oacc * inv);
}

extern "C" void kernel_launch(void* const* d_in, const int* in_sizes, int n_in,
                              void* d_out, int out_size, void* d_ws, size_t ws_size,
                              hipStream_t stream) {
  const float* x    = (const float*)d_in[0];
  const float* wq   = (const float*)d_in[1];
  const float* wk   = (const float*)d_in[2];
  const float* wv   = (const float*)d_in[3];
  const float* wo   = (const float*)d_in[4];
  const float* cosT = (const float*)d_in[5];
  const float* sinT = (const float*)d_in[6];
  const int*   posp = (const int*)d_in[8];
  float* out = (float*)d_out;

  char* ws = (char*)d_ws;
  size_t off = 0;
  auto alloc = [&](size_t bytes) {
    char* p = ws + off;
    off += (bytes + 255) & ~(size_t)255;
    return p;
  };
  unsigned short* xb  = (unsigned short*)alloc((size_t)B_ * S_ * D_ * 2);
  unsigned short* wft = (unsigned short*)alloc((size_t)NQKV * D_ * 2);   // [2560][2048] = wq^T|wk^T|wv^T
  unsigned short* wot = (unsigned short*)alloc((size_t)D_ * D_ * 2);     // wo^T
  float*          qkv = (float*)alloc((size_t)B_ * S_ * NQKV * 4);
  unsigned short* q_r = (unsigned short*)alloc((size_t)B_ * H_ * S_ * HD_ * 2);
  unsigned short* k_r = (unsigned short*)alloc((size_t)B_ * KV_ * S_ * HD_ * 2);
  unsigned short* v_c = (unsigned short*)alloc((size_t)B_ * KV_ * S_ * HD_ * 2);
  unsigned short* ao  = (unsigned short*)alloc((size_t)B_ * S_ * H_ * HD_ * 2);
  if (off > ws_size) return;  // workspace too small: fail visibly

  k_convert<<<(B_ * S_ * D_ / 4 + 255) / 256, 256, 0, stream>>>(x, xb, B_ * S_ * D_ / 4);
  k_transpose<<<dim3(D_ / 32, D_ / 32), 256, 0, stream>>>(wq, wft, D_, D_, 0, D_);
  k_transpose<<<dim3((KV_ * HD_) / 32, D_ / 32), 256, 0, stream>>>(wk, wft, D_, KV_ * HD_, 2048, D_);
  k_transpose<<<dim3((KV_ * HD_) / 32, D_ / 32), 256, 0, stream>>>(wv, wft, D_, KV_ * HD_, 2304, D_);
  k_transpose<<<dim3(D_ / 32, D_ / 32), 256, 0, stream>>>(wo, wot, D_, D_, 0, D_);

  k_gemm_bt<<<dim3(NQKV / 128, (B_ * S_) / 128), 256, 0, stream>>>(xb, wft, qkv, B_ * S_, NQKV, D_);

  k_rope_q<<<(B_ * S_ * H_ * 32) / 256, 256, 0, stream>>>(qkv, cosT, sinT, posp, q_r);
  k_rope_k<<<(B_ * S_ * KV_ * 32) / 256, 256, 0, stream>>>(qkv, cosT, sinT, posp, k_r);
  k_conv_v<<<(B_ * S_ * KV_ * 64) / 256, 256, 0, stream>>>(qkv, v_c);

  k_attn<<<dim3(S_ / 4, H_, B_), 256, 0, stream>>>(q_r, k_r, v_c, ao);

  k_gemm_bt<<<dim3(D_ / 128, (B_ * S_) / 128), 256, 0, stream>>>(ao, wot, out, B_ * S_, D_, D_);
}

// Round 2
// 171.756 us; speedup vs baseline: 5.2758x; 5.2758x over previous
//
#include <hip/hip_runtime.h>

#define B_ 2
#define S_ 1024
#define D_ 2048
#define H_ 32
#define KV_ 4
#define HD_ 64
#define NQKV 2560  // H*HD + KV*HD + KV*HD

typedef __attribute__((ext_vector_type(8))) short bf16x8;
typedef __attribute__((ext_vector_type(4))) float f32x4;

__device__ __forceinline__ unsigned short f2bf(float f) {
  unsigned int u = __float_as_uint(f);
  u = (u + 0x7fffu + ((u >> 16) & 1u)) >> 16;   // RNE
  return (unsigned short)u;
}

// ---------------- elementwise f32 -> bf16 ----------------
__global__ __launch_bounds__(256) void k_convert(const float* __restrict__ src,
                                                 unsigned short* __restrict__ dst, int n4) {
  int i = blockIdx.x * 256 + threadIdx.x;
  if (i >= n4) return;
  float4 v = ((const float4*)src)[i];
  ushort4 o;
  o.x = f2bf(v.x); o.y = f2bf(v.y); o.z = f2bf(v.z); o.w = f2bf(v.w);
  ((ushort4*)dst)[i] = o;
}

// ---------------- transpose f32 (K x N) -> bf16 (N x K), row offset into dst ----------------
__global__ __launch_bounds__(256) void k_transpose(const float* __restrict__ src,
                                                   unsigned short* __restrict__ dst,
                                                   int K, int N, int roff, int dld) {
  __shared__ float tile[32][33];
  int n0 = blockIdx.x * 32, k0 = blockIdx.y * 32;
  int tx = threadIdx.x & 31, ty = threadIdx.x >> 5;  // ty 0..7
  #pragma unroll
  for (int i = 0; i < 4; ++i)
    tile[ty + 8 * i][tx] = src[(size_t)(k0 + ty + 8 * i) * N + (n0 + tx)];
  __syncthreads();
  #pragma unroll
  for (int i = 0; i < 4; ++i)
    dst[(size_t)(roff + n0 + ty + 8 * i) * dld + (k0 + tx)] = f2bf(tile[tx][ty + 8 * i]);
}

// ---------------- GEMM: C[M][N] = A[M][K] * Bt[N][K]^T, bf16 in, f32 out ----------------
__global__ __launch_bounds__(256) void k_gemm_bt(const unsigned short* __restrict__ A,
                                                 const unsigned short* __restrict__ Bt,
                                                 float* __restrict__ C, int M, int N, int K) {
  __shared__ alignas(16) unsigned short As[128 * 64];
  __shared__ alignas(16) unsigned short Bs[128 * 64];
  const int tid = threadIdx.x;
  const int wid = tid >> 6, lane = tid & 63;
  const int m0 = blockIdx.y * 128, n0 = blockIdx.x * 128;
  const int wr = wid >> 1, wc = wid & 1;
  f32x4 acc[4][4] = {};

  const int nkt = K >> 6;
  for (int kt = 0; kt < nkt; ++kt) {
    __syncthreads();
    #pragma unroll
    for (int i = 0; i < 4; ++i) {
      int o = (wid * 4 + i) * 512 + lane * 8;
      int row = o >> 6;
      int kc = o & 63;
      const unsigned short* ga = A + (size_t)(m0 + row) * K + kt * 64 + kc;
      __builtin_amdgcn_global_load_lds((const __attribute__((address_space(1))) void*)ga,
                                       (__attribute__((address_space(3))) void*)(As + o), 16, 0, 0);
      const unsigned short* gb = Bt + (size_t)(n0 + row) * K + kt * 64 + kc;
      __builtin_amdgcn_global_load_lds((const __attribute__((address_space(1))) void*)gb,
                                       (__attribute__((address_space(3))) void*)(Bs + o), 16, 0, 0);
    }
    __syncthreads();
    #pragma unroll
    for (int ks = 0; ks < 2; ++ks) {
      bf16x8 a[4], b[4];
      #pragma unroll
      for (int m = 0; m < 4; ++m) {
        int row = wr * 64 + m * 16 + (lane & 15);
        int col = ks * 32 + ((lane >> 4) * 8);
        a[m] = *(const bf16x8*)(As + row * 64 + col);
      }
      #pragma unroll
      for (int n = 0; n < 4; ++n) {
        int row = wc * 64 + n * 16 + (lane & 15);
        int col = ks * 32 + ((lane >> 4) * 8);
        b[n] = *(const bf16x8*)(Bs + row * 64 + col);
      }
      #pragma unroll
      for (int m = 0; m < 4; ++m)
        #pragma unroll
        for (int n = 0; n < 4; ++n)
          acc[m][n] = __builtin_amdgcn_mfma_f32_16x16x32_bf16(a[m], b[n], acc[m][n], 0, 0, 0);
    }
  }
  const int cr = (lane >> 4) * 4;
  const int cc = lane & 15;
  #pragma unroll
  for (int m = 0; m < 4; ++m)
    #pragma unroll
    for (int n = 0; n < 4; ++n) {
      int col = n0 + wc * 64 + n * 16 + cc;
      int rowb = m0 + wr * 64 + m * 16 + cr;
      #pragma unroll
      for (int r = 0; r < 4; ++r)
        C[(size_t)(rowb + r) * N + col] = acc[m][n][r];
    }
}

// ---------------- RoPE q: qkv f32 -> q_r bf16 (B,H,S,HD) ----------------
__global__ __launch_bounds__(256) void k_rope_q(const float* __restrict__ qkv,
                                                const float* __restrict__ cosT,
                                                const float* __restrict__ sinT,
                                                const int* __restrict__ posp,
                                                unsigned short* __restrict__ q_r) {
  int t = blockIdx.x * 256 + threadIdx.x;
  int i = t & 31, h = (t >> 5) & 31, s = (t >> 10) & 1023, b = t >> 20;
  int pos = posp[0];
  const float* row = qkv + (size_t)(b * S_ + s) * NQKV + h * HD_;
  float q1 = row[i], q2 = row[i + 32];
  float c = cosT[(pos + s) * 32 + i], sn = sinT[(pos + s) * 32 + i];
  size_t o = ((size_t)(b * H_ + h) * S_ + s) * HD_ + i;
  q_r[o] = f2bf(q1 * c - q2 * sn);
  q_r[o + 32] = f2bf(q2 * c + q1 * sn);
}

// ---------------- RoPE k: qkv f32 -> k_r bf16 (B,KV,S,HD) ----------------
__global__ __launch_bounds__(256) void k_rope_k(const float* __restrict__ qkv,
                                                const float* __restrict__ cosT,
                                                const float* __restrict__ sinT,
                                                const int* __restrict__ posp,
                                                unsigned short* __restrict__ k_r) {
  int t = blockIdx.x * 256 + threadIdx.x;
  int i = t & 31, g = (t >> 5) & 3, s = (t >> 7) & 1023, b = t >> 17;
  int pos = posp[0];
  const float* row = qkv + (size_t)(b * S_ + s) * NQKV + 2048 + g * HD_;
  float k1 = row[i], k2 = row[i + 32];
  float c = cosT[(pos + s) * 32 + i], sn = sinT[(pos + s) * 32 + i];
  size_t o = ((size_t)(b * KV_ + g) * S_ + s) * HD_ + i;
  k_r[o] = f2bf(k1 * c - k2 * sn);
  k_r[o + 32] = f2bf(k2 * c + k1 * sn);
}

// ---------------- v: qkv f32 -> v_t bf16 (B,KV,HD,S)  (transposed for PV A-operand) ---------
__global__ __launch_bounds__(256) void k_conv_vt(const float* __restrict__ qkv,
                                                 unsigned short* __restrict__ v_t) {
  __shared__ float tile[32][33];
  int bg = blockIdx.z;           // b*KV+g
  int b = bg >> 2, g = bg & 3;
  int s0 = blockIdx.x * 32, d0 = blockIdx.y * 32;
  int tx = threadIdx.x & 31, ty = threadIdx.x >> 5;
  #pragma unroll
  for (int i = 0; i < 4; ++i) {
    int s = s0 + ty + 8 * i;
    tile[ty + 8 * i][tx] = qkv[(size_t)(b * S_ + s) * NQKV + 2304 + g * HD_ + d0 + tx];
  }
  __syncthreads();
  #pragma unroll
  for (int i = 0; i < 4; ++i) {
    int d = d0 + ty + 8 * i;
    v_t[((size_t)bg * HD_ + d) * S_ + s0 + tx] = f2bf(tile[tx][ty + 8 * i]);
  }
}

// ---------------- MFMA flash attention (swapped QK^T, in-register softmax) ----------------
// grid (S/64, H, B), 4 waves; wave owns 16 q-rows. KV chunk 64.
__global__ __launch_bounds__(256) void k_attn(const unsigned short* __restrict__ qr,
                                              const unsigned short* __restrict__ kr,
                                              const unsigned short* __restrict__ vt,
                                              unsigned short* __restrict__ ao) {
  __shared__ alignas(16) unsigned short k_lds[64 * 64];  // rows j, 16B-chunk XOR-swizzled
  __shared__ alignas(16) unsigned short v_lds[64 * 64];  // rows d, same swizzle
  const int tid = threadIdx.x;
  const int wid = tid >> 6, lane = tid & 63;
  const int lo = lane & 15, hi = lane >> 4;
  const int b = blockIdx.z, h = blockIdx.y, g = h >> 3;
  const int qt = blockIdx.x;
  const int qb = qt * 64 + wid * 16;
  const int q = qb + lo;                 // this lane's q row (S^T col)

  // Q B-fragment, loaded once: B[d][q], lane reads Q[qb+lo][ks*32 + hi*8 ..]
  const unsigned short* qrow = qr + ((size_t)(b * H_ + h) * S_ + q) * HD_;
  bf16x8 qf[2];
  qf[0] = *(const bf16x8*)(qrow + hi * 8);
  qf[1] = *(const bf16x8*)(qrow + 32 + hi * 8);

  const unsigned short* kbase = kr + (size_t)(b * KV_ + g) * S_ * HD_;
  const unsigned short* vbase = vt + (size_t)(b * KV_ + g) * HD_ * S_;

  f32x4 oacc[4] = {};                    // O^T tiles: d = dt*16 + hi*4 + rr, col q = lo
  float mrun = -1e30f, lrun = 0.f;
  const float kscale = 0.125f;           // 1/sqrt(64)

  for (int c = 0; c <= qt; ++c) {
    const int j0 = c * 64;
    __syncthreads();
    // stage K chunk + Vt chunk; LDS linear, source chunk pre-swizzled (involution)
    #pragma unroll
    for (int i = 0; i < 2; ++i) {
      int u = i * 256 + tid;             // 16B unit, 0..511
      int r = u >> 3, ch = u & 7;
      int chs = ch ^ (r & 7);
      const unsigned short* gk = kbase + (size_t)(j0 + r) * HD_ + chs * 8;
      __builtin_amdgcn_global_load_lds((const __attribute__((address_space(1))) void*)gk,
                                       (__attribute__((address_space(3))) void*)(k_lds + u * 8), 16, 0, 0);
      const unsigned short* gv = vbase + (size_t)r * S_ + j0 + chs * 8;
      __builtin_amdgcn_global_load_lds((const __attribute__((address_space(1))) void*)gv,
                                       (__attribute__((address_space(3))) void*)(v_lds + u * 8), 16, 0, 0);
    }
    __syncthreads();

    // S^T = K · Q^T : acc col = q (lo), row = j_rel (hi*4+rr), tile jt
    f32x4 st[4];
    #pragma unroll
    for (int jt = 0; jt < 4; ++jt) st[jt] = (f32x4){0.f, 0.f, 0.f, 0.f};
    #pragma unroll
    for (int ks = 0; ks < 2; ++ks)
      #pragma unroll
      for (int jt = 0; jt < 4; ++jt) {
        int row = jt * 16 + lo;
        int chs = (ks * 4 + hi) ^ (lo & 7);
        bf16x8 kf = *(const bf16x8*)(k_lds + row * 64 + chs * 8);
        st[jt] = __builtin_amdgcn_mfma_f32_16x16x32_bf16(kf, qf[ks], st[jt], 0, 0, 0);
      }

    // scale + causal mask (only diagonal chunk), local max over this lane's 16 scores
    const bool diag = (c == qt);
    float pmax = -1e30f;
    #pragma unroll
    for (int jt = 0; jt < 4; ++jt)
      #pragma unroll
      for (int rr = 0; rr < 4; ++rr) {
        float sc = st[jt][rr] * kscale;
        if (diag && (j0 + jt * 16 + hi * 4 + rr > q)) sc = -1e30f;
        st[jt][rr] = sc;
        pmax = fmaxf(pmax, sc);
      }
    // row-reduce across the 4 hi-groups (same q = lo)
    pmax = fmaxf(pmax, __shfl_xor(pmax, 16, 64));
    pmax = fmaxf(pmax, __shfl_xor(pmax, 32, 64));
    float mn = fmaxf(mrun, pmax);
    float scale = __expf(mrun - mn);
    float ps = 0.f;
    #pragma unroll
    for (int jt = 0; jt < 4; ++jt)
      #pragma unroll
      for (int rr = 0; rr < 4; ++rr) {
        float e = __expf(st[jt][rr] - mn);
        st[jt][rr] = e;
        ps += e;
      }
    ps += __shfl_xor(ps, 16, 64);
    ps += __shfl_xor(ps, 32, 64);
    lrun = lrun * scale + ps;
    mrun = mn;
    #pragma unroll
    for (int dt = 0; dt < 4; ++dt)
      #pragma unroll
      for (int rr = 0; rr < 4; ++rr) oacc[dt][rr] *= scale;

    // pack P^T to bf16 pairs: pk[jt][cpair] = {rr=2c (lo16), rr=2c+1 (hi16)}
    unsigned int pk[4][2];
    #pragma unroll
    for (int jt = 0; jt < 4; ++jt)
      #pragma unroll
      for (int cp = 0; cp < 2; ++cp)
        pk[jt][cp] = (unsigned int)f2bf(st[jt][2 * cp]) |
                     ((unsigned int)f2bf(st[jt][2 * cp + 1]) << 16);

    // redistribute P^T into PV B-fragments: lane needs B[j=hi*8+jj][q=lo]
    int s0l = ((hi & 1) << 5) + lo;   // source lane hi_src = 2*(hi&1)
    int s1l = s0l + 16;               // hi_src + 1
    bool hb = (hi & 2) != 0;          // selects jt' = 2ks + (hi>>1)
    bf16x8 pf[2];
    #pragma unroll
    for (int ks = 0; ks < 2; ++ks) {
      unsigned int a0 = __shfl((int)pk[2 * ks][0], s0l, 64);
      unsigned int b0 = __shfl((int)pk[2 * ks + 1][0], s0l, 64);
      unsigned int a1 = __shfl((int)pk[2 * ks][1], s0l, 64);
      unsigned int b1 = __shfl((int)pk[2 * ks + 1][1], s0l, 64);
      unsigned int a2 = __shfl((int)pk[2 * ks][0], s1l, 64);
      unsigned int b2 = __shfl((int)pk[2 * ks + 1][0], s1l, 64);
      unsigned int a3 = __shfl((int)pk[2 * ks][1], s1l, 64);
      unsigned int b3 = __shfl((int)pk[2 * ks + 1][1], s1l, 64);
      union { unsigned int u[4]; bf16x8 v; } cvt;
      cvt.u[0] = hb ? b0 : a0;
      cvt.u[1] = hb ? b1 : a1;
      cvt.u[2] = hb ? b2 : a2;
      cvt.u[3] = hb ? b3 : a3;
      pf[ks] = cvt.v;
    }

    // O^T += Vt · P^T : A = Vt rows d, B = P^T
    #pragma unroll
    for (int ks = 0; ks < 2; ++ks)
      #pragma unroll
      for (int dt = 0; dt < 4; ++dt) {
        int row = dt * 16 + lo;
        int chs = (ks * 4 + hi) ^ (lo & 7);
        bf16x8 vf = *(const bf16x8*)(v_lds + row * 64 + chs * 8);
        oacc[dt] = __builtin_amdgcn_mfma_f32_16x16x32_bf16(vf, pf[ks], oacc[dt], 0, 0, 0);
      }
  }

  float inv = 1.f / lrun;
  #pragma unroll
  for (int dt = 0; dt < 4; ++dt) {
    ushort4 o;
    o.x = f2bf(oacc[dt][0] * inv);
    o.y = f2bf(oacc[dt][1] * inv);
    o.z = f2bf(oacc[dt][2] * inv);
    o.w = f2bf(oacc[dt][3] * inv);
    *(ushort4*)(ao + ((size_t)(b * S_ + q)) * (H_ * HD_) + h * HD_ + dt * 16 + hi * 4) = o;
  }
}

extern "C" void kernel_launch(void* const* d_in, const int* in_sizes, int n_in,
                              void* d_out, int out_size, void* d_ws, size_t ws_size,
                              hipStream_t stream) {
  const float* x    = (const float*)d_in[0];
  const float* wq   = (const float*)d_in[1];
  const float* wk   = (const float*)d_in[2];
  const float* wv   = (const float*)d_in[3];
  const float* wo   = (const float*)d_in[4];
  const float* cosT = (const float*)d_in[5];
  const float* sinT = (const float*)d_in[6];
  const int*   posp = (const int*)d_in[8];
  float* out = (float*)d_out;

  char* ws = (char*)d_ws;
  size_t off = 0;
  auto alloc = [&](size_t bytes) {
    char* p = ws + off;
    off += (bytes + 255) & ~(size_t)255;
    return p;
  };
  unsigned short* xb  = (unsigned short*)alloc((size_t)B_ * S_ * D_ * 2);
  unsigned short* wft = (unsigned short*)alloc((size_t)NQKV * D_ * 2);
  unsigned short* wot = (unsigned short*)alloc((size_t)D_ * D_ * 2);
  float*          qkv = (float*)alloc((size_t)B_ * S_ * NQKV * 4);
  unsigned short* q_r = (unsigned short*)alloc((size_t)B_ * H_ * S_ * HD_ * 2);
  unsigned short* k_r = (unsigned short*)alloc((size_t)B_ * KV_ * S_ * HD_ * 2);
  unsigned short* v_t = (unsigned short*)alloc((size_t)B_ * KV_ * HD_ * S_ * 2);
  unsigned short* ao  = (unsigned short*)alloc((size_t)B_ * S_ * H_ * HD_ * 2);
  if (off > ws_size) return;

  k_convert<<<(B_ * S_ * D_ / 4 + 255) / 256, 256, 0, stream>>>(x, xb, B_ * S_ * D_ / 4);
  k_transpose<<<dim3(D_ / 32, D_ / 32), 256, 0, stream>>>(wq, wft, D_, D_, 0, D_);
  k_transpose<<<dim3((KV_ * HD_) / 32, D_ / 32), 256, 0, stream>>>(wk, wft, D_, KV_ * HD_, 2048, D_);
  k_transpose<<<dim3((KV_ * HD_) / 32, D_ / 32), 256, 0, stream>>>(wv, wft, D_, KV_ * HD_, 2304, D_);
  k_transpose<<<dim3(D_ / 32, D_ / 32), 256, 0, stream>>>(wo, wot, D_, D_, 0, D_);

  k_gemm_bt<<<dim3(NQKV / 128, (B_ * S_) / 128), 256, 0, stream>>>(xb, wft, qkv, B_ * S_, NQKV, D_);

  k_rope_q<<<(B_ * S_ * H_ * 32) / 256, 256, 0, stream>>>(qkv, cosT, sinT, posp, q_r);
  k_rope_k<<<(B_ * S_ * KV_ * 32) / 256, 256, 0, stream>>>(qkv, cosT, sinT, posp, k_r);
  k_conv_vt<<<dim3(S_ / 32, HD_ / 32, B_ * KV_), 256, 0, stream>>>(qkv, v_t);

  k_attn<<<dim3(S_ / 64, H_, B_), 256, 0, stream>>>(q_r, k_r, v_t, ao);

  k_gemm_bt<<<dim3(D_ / 128, (B_ * S_) / 128), 256, 0, stream>>>(ao, wot, out, B_ * S_, D_, D_);
}

// Round 3
// 127.333 us; speedup vs baseline: 7.1163x; 1.3489x over previous
//
#include <hip/hip_runtime.h>

#define B_ 2
#define S_ 1024
#define D_ 2048
#define H_ 32
#define KV_ 4
#define HD_ 64
#define NQKV 2560  // H*HD + KV*HD + KV*HD

typedef __attribute__((ext_vector_type(8))) short bf16x8;
typedef __attribute__((ext_vector_type(4))) float f32x4;

__device__ __forceinline__ unsigned short f2bf(float f) {
  unsigned int u = __float_as_uint(f);
  u = (u + 0x7fffu + ((u >> 16) & 1u)) >> 16;   // RNE
  return (unsigned short)u;
}

// ---------------- elementwise f32 -> bf16 ----------------
__global__ __launch_bounds__(256) void k_convert(const float* __restrict__ src,
                                                 unsigned short* __restrict__ dst, int n4) {
  int i = blockIdx.x * 256 + threadIdx.x;
  if (i >= n4) return;
  float4 v = ((const float4*)src)[i];
  ushort4 o;
  o.x = f2bf(v.x); o.y = f2bf(v.y); o.z = f2bf(v.z); o.w = f2bf(v.w);
  ((ushort4*)dst)[i] = o;
}

// ---------------- transpose f32 (K x N) -> bf16 (N x K), row offset into dst ----------------
__global__ __launch_bounds__(256) void k_transpose(const float* __restrict__ src,
                                                   unsigned short* __restrict__ dst,
                                                   int K, int N, int roff, int dld) {
  __shared__ float tile[32][33];
  int n0 = blockIdx.x * 32, k0 = blockIdx.y * 32;
  int tx = threadIdx.x & 31, ty = threadIdx.x >> 5;  // ty 0..7
  #pragma unroll
  for (int i = 0; i < 4; ++i)
    tile[ty + 8 * i][tx] = src[(size_t)(k0 + ty + 8 * i) * N + (n0 + tx)];
  __syncthreads();
  #pragma unroll
  for (int i = 0; i < 4; ++i)
    dst[(size_t)(roff + n0 + ty + 8 * i) * dld + (k0 + tx)] = f2bf(tile[tx][ty + 8 * i]);
}

// ---------------- GEMM: C[M][N] = A[M][K] * Bt[N][K]^T, bf16 in ----------------
// BM x BN tile, BK=64, 4 waves (2x2, each (BM/2)x(BN/2)), LDS XOR-swizzled.
// MODE 0: plain f32 C write. MODE 1: fused QKV epilogue (RoPE q/k, V transpose, bf16).
template <int BM, int BN, int MODE>
__global__ __launch_bounds__(256) void k_gemm(const unsigned short* __restrict__ A,
                                              const unsigned short* __restrict__ Bt,
                                              float* __restrict__ C,
                                              const float* __restrict__ cosT,
                                              const float* __restrict__ sinT,
                                              const int* __restrict__ posp,
                                              unsigned short* __restrict__ q_r,
                                              unsigned short* __restrict__ k_r,
                                              unsigned short* __restrict__ v_t,
                                              int M, int N, int K) {
  constexpr int MR = BM / 32;  // frag rows per wave
  constexpr int NR = BN / 32;  // frag cols per wave
  __shared__ alignas(16) unsigned short As[BM * 64];
  __shared__ alignas(16) unsigned short Bs[BN * 64];
  const int tid = threadIdx.x;
  const int wid = tid >> 6, lane = tid & 63;
  const int lo = lane & 15, hi = lane >> 4;
  const int m0 = blockIdx.y * BM, n0 = blockIdx.x * BN;
  const int wr = wid >> 1, wc = wid & 1;
  f32x4 acc[MR][NR] = {};

  const int nkt = K >> 6;
  for (int kt = 0; kt < nkt; ++kt) {
    __syncthreads();
    // stage A, B: linear LDS dest, source 16B-chunk XOR-preswizzled (involution)
    #pragma unroll
    for (int u = tid; u < BM * 8; u += 256) {
      int row = u >> 3, ch = u & 7, chs = ch ^ (row & 7);
      const unsigned short* ga = A + (size_t)(m0 + row) * K + kt * 64 + chs * 8;
      __builtin_amdgcn_global_load_lds((const __attribute__((address_space(1))) void*)ga,
                                       (__attribute__((address_space(3))) void*)(As + u * 8), 16, 0, 0);
    }
    #pragma unroll
    for (int u = tid; u < BN * 8; u += 256) {
      int row = u >> 3, ch = u & 7, chs = ch ^ (row & 7);
      const unsigned short* gb = Bt + (size_t)(n0 + row) * K + kt * 64 + chs * 8;
      __builtin_amdgcn_global_load_lds((const __attribute__((address_space(1))) void*)gb,
                                       (__attribute__((address_space(3))) void*)(Bs + u * 8), 16, 0, 0);
    }
    __syncthreads();
    #pragma unroll
    for (int ks = 0; ks < 2; ++ks) {
      const int chs = (ks * 4 + hi) ^ (lo & 7);
      bf16x8 a[MR], b[NR];
      #pragma unroll
      for (int m = 0; m < MR; ++m) {
        int row = wr * (BM / 2) + m * 16 + lo;
        a[m] = *(const bf16x8*)(As + row * 64 + chs * 8);
      }
      #pragma unroll
      for (int n = 0; n < NR; ++n) {
        int row = wc * (BN / 2) + n * 16 + lo;
        b[n] = *(const bf16x8*)(Bs + row * 64 + chs * 8);
      }
      #pragma unroll
      for (int m = 0; m < MR; ++m)
        #pragma unroll
        for (int n = 0; n < NR; ++n)
          acc[m][n] = __builtin_amdgcn_mfma_f32_16x16x32_bf16(a[m], b[n], acc[m][n], 0, 0, 0);
    }
  }

  if (MODE == 0) {
    const int cr = hi * 4;
    #pragma unroll
    for (int m = 0; m < MR; ++m)
      #pragma unroll
      for (int n = 0; n < NR; ++n) {
        int col = n0 + wc * (BN / 2) + n * 16 + lo;
        int rowb = m0 + wr * (BM / 2) + m * 16 + cr;
        #pragma unroll
        for (int r = 0; r < 4; ++r)
          C[(size_t)(rowb + r) * N + col] = acc[m][n][r];
      }
  } else {
    // QKV epilogue. Wave col span = 64 = one head/group. NR must be 4.
    const int col0 = n0 + wc * (BN / 2);
    const int pos = posp[0];
    if (col0 < 2048) {            // ---- Q + RoPE ----
      const int h = col0 >> 6;
      #pragma unroll
      for (int m = 0; m < MR; ++m)
        #pragma unroll
        for (int r = 0; r < 4; ++r) {
          int row = m0 + wr * (BM / 2) + m * 16 + hi * 4 + r;
          int s = row & (S_ - 1), b = row >> 10;
          unsigned short* base = q_r + ((size_t)(b * H_ + h) * S_ + s) * HD_;
          #pragma unroll
          for (int np = 0; np < 2; ++np) {
            int i = np * 16 + lo;
            float t1 = acc[m][np][r], t2 = acc[m][np + 2][r];
            float c = cosT[(size_t)(pos + s) * 32 + i];
            float sn = sinT[(size_t)(pos + s) * 32 + i];
            base[i] = f2bf(t1 * c - t2 * sn);
            base[i + 32] = f2bf(t2 * c + t1 * sn);
          }
        }
    } else if (col0 < 2304) {     // ---- K + RoPE ----
      const int g = (col0 - 2048) >> 6;
      #pragma unroll
      for (int m = 0; m < MR; ++m)
        #pragma unroll
        for (int r = 0; r < 4; ++r) {
          int row = m0 + wr * (BM / 2) + m * 16 + hi * 4 + r;
          int s = row & (S_ - 1), b = row >> 10;
          unsigned short* base = k_r + ((size_t)(b * KV_ + g) * S_ + s) * HD_;
          #pragma unroll
          for (int np = 0; np < 2; ++np) {
            int i = np * 16 + lo;
            float t1 = acc[m][np][r], t2 = acc[m][np + 2][r];
            float c = cosT[(size_t)(pos + s) * 32 + i];
            float sn = sinT[(size_t)(pos + s) * 32 + i];
            base[i] = f2bf(t1 * c - t2 * sn);
            base[i + 32] = f2bf(t2 * c + t1 * sn);
          }
        }
    } else {                      // ---- V -> (B,KV,HD,S) transposed bf16 ----
      const int g = (col0 - 2304) >> 6;
      #pragma unroll
      for (int m = 0; m < MR; ++m) {
        int row0 = m0 + wr * (BM / 2) + m * 16 + hi * 4;
        int s0 = row0 & (S_ - 1), b = row0 >> 10;
        #pragma unroll
        for (int n = 0; n < NR; ++n) {
          int d = n * 16 + lo;
          ushort4 o;
          o.x = f2bf(acc[m][n][0]);
          o.y = f2bf(acc[m][n][1]);
          o.z = f2bf(acc[m][n][2]);
          o.w = f2bf(acc[m][n][3]);
          *(ushort4*)(v_t + ((size_t)(b * KV_ + g) * HD_ + d) * S_ + s0) = o;
        }
      }
    }
  }
}

// ---------------- MFMA flash attention (swapped QK^T, in-register softmax) ----------------
// grid (S/64, H, B), 4 waves; wave owns 16 q-rows. KV chunk 64.
__global__ __launch_bounds__(256) void k_attn(const unsigned short* __restrict__ qr,
                                              const unsigned short* __restrict__ kr,
                                              const unsigned short* __restrict__ vt,
                                              unsigned short* __restrict__ ao) {
  __shared__ alignas(16) unsigned short k_lds[64 * 64];  // rows j, 16B-chunk XOR-swizzled
  __shared__ alignas(16) unsigned short v_lds[64 * 64];  // rows d, same swizzle
  const int tid = threadIdx.x;
  const int wid = tid >> 6, lane = tid & 63;
  const int lo = lane & 15, hi = lane >> 4;
  const int b = blockIdx.z, h = blockIdx.y, g = h >> 3;
  const int qt = blockIdx.x;
  const int qb = qt * 64 + wid * 16;
  const int q = qb + lo;                 // this lane's q row (S^T col)

  const unsigned short* qrow = qr + ((size_t)(b * H_ + h) * S_ + q) * HD_;
  bf16x8 qf[2];
  qf[0] = *(const bf16x8*)(qrow + hi * 8);
  qf[1] = *(const bf16x8*)(qrow + 32 + hi * 8);

  const unsigned short* kbase = kr + (size_t)(b * KV_ + g) * S_ * HD_;
  const unsigned short* vbase = vt + (size_t)(b * KV_ + g) * HD_ * S_;

  f32x4 oacc[4] = {};                    // O^T tiles: d = dt*16 + hi*4 + rr, col q = lo
  float mrun = -1e30f, lrun = 0.f;
  const float kscale = 0.125f;           // 1/sqrt(64)

  for (int c = 0; c <= qt; ++c) {
    const int j0 = c * 64;
    __syncthreads();
    #pragma unroll
    for (int i = 0; i < 2; ++i) {
      int u = i * 256 + tid;             // 16B unit, 0..511
      int r = u >> 3, ch = u & 7;
      int chs = ch ^ (r & 7);
      const unsigned short* gk = kbase + (size_t)(j0 + r) * HD_ + chs * 8;
      __builtin_amdgcn_global_load_lds((const __attribute__((address_space(1))) void*)gk,
                                       (__attribute__((address_space(3))) void*)(k_lds + u * 8), 16, 0, 0);
      const unsigned short* gv = vbase + (size_t)r * S_ + j0 + chs * 8;
      __builtin_amdgcn_global_load_lds((const __attribute__((address_space(1))) void*)gv,
                                       (__attribute__((address_space(3))) void*)(v_lds + u * 8), 16, 0, 0);
    }
    __syncthreads();

    // S^T = K · Q^T
    f32x4 st[4];
    #pragma unroll
    for (int jt = 0; jt < 4; ++jt) st[jt] = (f32x4){0.f, 0.f, 0.f, 0.f};
    #pragma unroll
    for (int ks = 0; ks < 2; ++ks)
      #pragma unroll
      for (int jt = 0; jt < 4; ++jt) {
        int row = jt * 16 + lo;
        int chs = (ks * 4 + hi) ^ (lo & 7);
        bf16x8 kf = *(const bf16x8*)(k_lds + row * 64 + chs * 8);
        st[jt] = __builtin_amdgcn_mfma_f32_16x16x32_bf16(kf, qf[ks], st[jt], 0, 0, 0);
      }

    const bool diag = (c == qt);
    float pmax = -1e30f;
    #pragma unroll
    for (int jt = 0; jt < 4; ++jt)
      #pragma unroll
      for (int rr = 0; rr < 4; ++rr) {
        float sc = st[jt][rr] * kscale;
        if (diag && (j0 + jt * 16 + hi * 4 + rr > q)) sc = -1e30f;
        st[jt][rr] = sc;
        pmax = fmaxf(pmax, sc);
      }
    pmax = fmaxf(pmax, __shfl_xor(pmax, 16, 64));
    pmax = fmaxf(pmax, __shfl_xor(pmax, 32, 64));
    float mn = fmaxf(mrun, pmax);
    float scale = __expf(mrun - mn);
    float ps = 0.f;
    #pragma unroll
    for (int jt = 0; jt < 4; ++jt)
      #pragma unroll
      for (int rr = 0; rr < 4; ++rr) {
        float e = __expf(st[jt][rr] - mn);
        st[jt][rr] = e;
        ps += e;
      }
    ps += __shfl_xor(ps, 16, 64);
    ps += __shfl_xor(ps, 32, 64);
    lrun = lrun * scale + ps;
    mrun = mn;
    #pragma unroll
    for (int dt = 0; dt < 4; ++dt)
      #pragma unroll
      for (int rr = 0; rr < 4; ++rr) oacc[dt][rr] *= scale;

    unsigned int pk[4][2];
    #pragma unroll
    for (int jt = 0; jt < 4; ++jt)
      #pragma unroll
      for (int cp = 0; cp < 2; ++cp)
        pk[jt][cp] = (unsigned int)f2bf(st[jt][2 * cp]) |
                     ((unsigned int)f2bf(st[jt][2 * cp + 1]) << 16);

    int s0l = ((hi & 1) << 5) + lo;
    int s1l = s0l + 16;
    bool hb = (hi & 2) != 0;
    bf16x8 pf[2];
    #pragma unroll
    for (int ks = 0; ks < 2; ++ks) {
      unsigned int a0 = __shfl((int)pk[2 * ks][0], s0l, 64);
      unsigned int b0 = __shfl((int)pk[2 * ks + 1][0], s0l, 64);
      unsigned int a1 = __shfl((int)pk[2 * ks][1], s0l, 64);
      unsigned int b1 = __shfl((int)pk[2 * ks + 1][1], s0l, 64);
      unsigned int a2 = __shfl((int)pk[2 * ks][0], s1l, 64);
      unsigned int b2 = __shfl((int)pk[2 * ks + 1][0], s1l, 64);
      unsigned int a3 = __shfl((int)pk[2 * ks][1], s1l, 64);
      unsigned int b3 = __shfl((int)pk[2 * ks + 1][1], s1l, 64);
      union { unsigned int u[4]; bf16x8 v; } cvt;
      cvt.u[0] = hb ? b0 : a0;
      cvt.u[1] = hb ? b1 : a1;
      cvt.u[2] = hb ? b2 : a2;
      cvt.u[3] = hb ? b3 : a3;
      pf[ks] = cvt.v;
    }

    #pragma unroll
    for (int ks = 0; ks < 2; ++ks)
      #pragma unroll
      for (int dt = 0; dt < 4; ++dt) {
        int row = dt * 16 + lo;
        int chs = (ks * 4 + hi) ^ (lo & 7);
        bf16x8 vf = *(const bf16x8*)(v_lds + row * 64 + chs * 8);
        oacc[dt] = __builtin_amdgcn_mfma_f32_16x16x32_bf16(vf, pf[ks], oacc[dt], 0, 0, 0);
      }
  }

  float inv = 1.f / lrun;
  #pragma unroll
  for (int dt = 0; dt < 4; ++dt) {
    ushort4 o;
    o.x = f2bf(oacc[dt][0] * inv);
    o.y = f2bf(oacc[dt][1] * inv);
    o.z = f2bf(oacc[dt][2] * inv);
    o.w = f2bf(oacc[dt][3] * inv);
    *(ushort4*)(ao + ((size_t)(b * S_ + q)) * (H_ * HD_) + h * HD_ + dt * 16 + hi * 4) = o;
  }
}

extern "C" void kernel_launch(void* const* d_in, const int* in_sizes, int n_in,
                              void* d_out, int out_size, void* d_ws, size_t ws_size,
                              hipStream_t stream) {
  const float* x    = (const float*)d_in[0];
  const float* wq   = (const float*)d_in[1];
  const float* wk   = (const float*)d_in[2];
  const float* wv   = (const float*)d_in[3];
  const float* wo   = (const float*)d_in[4];
  const float* cosT = (const float*)d_in[5];
  const float* sinT = (const float*)d_in[6];
  const int*   posp = (const int*)d_in[8];
  float* out = (float*)d_out;

  char* ws = (char*)d_ws;
  size_t off = 0;
  auto alloc = [&](size_t bytes) {
    char* p = ws + off;
    off += (bytes + 255) & ~(size_t)255;
    return p;
  };
  unsigned short* xb  = (unsigned short*)alloc((size_t)B_ * S_ * D_ * 2);
  unsigned short* wft = (unsigned short*)alloc((size_t)NQKV * D_ * 2);
  unsigned short* wot = (unsigned short*)alloc((size_t)D_ * D_ * 2);
  unsigned short* q_r = (unsigned short*)alloc((size_t)B_ * H_ * S_ * HD_ * 2);
  unsigned short* k_r = (unsigned short*)alloc((size_t)B_ * KV_ * S_ * HD_ * 2);
  unsigned short* v_t = (unsigned short*)alloc((size_t)B_ * KV_ * HD_ * S_ * 2);
  unsigned short* ao  = (unsigned short*)alloc((size_t)B_ * S_ * H_ * HD_ * 2);
  if (off > ws_size) return;

  k_convert<<<(B_ * S_ * D_ / 4 + 255) / 256, 256, 0, stream>>>(x, xb, B_ * S_ * D_ / 4);
  k_transpose<<<dim3(D_ / 32, D_ / 32), 256, 0, stream>>>(wq, wft, D_, D_, 0, D_);
  k_transpose<<<dim3((KV_ * HD_) / 32, D_ / 32), 256, 0, stream>>>(wk, wft, D_, KV_ * HD_, 2048, D_);
  k_transpose<<<dim3((KV_ * HD_) / 32, D_ / 32), 256, 0, stream>>>(wv, wft, D_, KV_ * HD_, 2304, D_);
  k_transpose<<<dim3(D_ / 32, D_ / 32), 256, 0, stream>>>(wo, wot, D_, D_, 0, D_);

  // QKV GEMM with fused RoPE / V-transpose epilogue: 64x128 tiles -> 640 blocks
  k_gemm<64, 128, 1><<<dim3(NQKV / 128, (B_ * S_) / 64), 256, 0, stream>>>(
      xb, wft, nullptr, cosT, sinT, posp, q_r, k_r, v_t, B_ * S_, NQKV, D_);

  k_attn<<<dim3(S_ / 64, H_, B_), 256, 0, stream>>>(q_r, k_r, v_t, ao);

  // Output GEMM: 64x128 tiles -> 512 blocks
  k_gemm<64, 128, 0><<<dim3(D_ / 128, (B_ * S_) / 64), 256, 0, stream>>>(
      ao, wot, out, nullptr, nullptr, nullptr, nullptr, nullptr, nullptr, B_ * S_, D_, D_);
}

// Round 4
// 116.749 us; speedup vs baseline: 7.7614x; 1.0907x over previous
//
#include <hip/hip_runtime.h>

#define B_ 2
#define S_ 1024
#define D_ 2048
#define H_ 32
#define KV_ 4
#define HD_ 64
#define NQKV 2560  // H*HD + KV*HD + KV*HD

typedef __attribute__((ext_vector_type(8))) short bf16x8;
typedef __attribute__((ext_vector_type(4))) float f32x4;

__device__ __forceinline__ unsigned short f2bf(float f) {
  unsigned int u = __float_as_uint(f);
  u = (u + 0x7fffu + ((u >> 16) & 1u)) >> 16;   // RNE
  return (unsigned short)u;
}

// ---------------- elementwise f32 -> bf16 ----------------
__global__ __launch_bounds__(256) void k_convert(const float* __restrict__ src,
                                                 unsigned short* __restrict__ dst, int n4) {
  int i = blockIdx.x * 256 + threadIdx.x;
  if (i >= n4) return;
  float4 v = ((const float4*)src)[i];
  ushort4 o;
  o.x = f2bf(v.x); o.y = f2bf(v.y); o.z = f2bf(v.z); o.w = f2bf(v.w);
  ((ushort4*)dst)[i] = o;
}

// ---------------- transpose f32 (K x N) -> bf16 (N x K), row offset into dst ----------------
__global__ __launch_bounds__(256) void k_transpose(const float* __restrict__ src,
                                                   unsigned short* __restrict__ dst,
                                                   int K, int N, int roff, int dld) {
  __shared__ float tile[32][33];
  int n0 = blockIdx.x * 32, k0 = blockIdx.y * 32;
  int tx = threadIdx.x & 31, ty = threadIdx.x >> 5;  // ty 0..7
  #pragma unroll
  for (int i = 0; i < 4; ++i)
    tile[ty + 8 * i][tx] = src[(size_t)(k0 + ty + 8 * i) * N + (n0 + tx)];
  __syncthreads();
  #pragma unroll
  for (int i = 0; i < 4; ++i)
    dst[(size_t)(roff + n0 + ty + 8 * i) * dld + (k0 + tx)] = f2bf(tile[tx][ty + 8 * i]);
}

// ---------------- GEMM: C[M][N] = A[M][K] * Bt[N][K]^T, bf16 in ----------------
// BM x BN tile, BK=64, 4 waves (2x2, each (BM/2)x(BN/2)), LDS XOR-swizzled.
// MODE 0: plain f32 C write. MODE 1: fused QKV epilogue (RoPE q/k, V transpose, bf16).
template <int BM, int BN, int MODE>
__global__ __launch_bounds__(256) void k_gemm(const unsigned short* __restrict__ A,
                                              const unsigned short* __restrict__ Bt,
                                              float* __restrict__ C,
                                              const float* __restrict__ cosT,
                                              const float* __restrict__ sinT,
                                              const int* __restrict__ posp,
                                              unsigned short* __restrict__ q_r,
                                              unsigned short* __restrict__ k_r,
                                              unsigned short* __restrict__ v_t,
                                              int M, int N, int K) {
  constexpr int MR = BM / 32;  // frag rows per wave
  constexpr int NR = BN / 32;  // frag cols per wave
  __shared__ alignas(16) unsigned short As[BM * 64];
  __shared__ alignas(16) unsigned short Bs[BN * 64];
  const int tid = threadIdx.x;
  const int wid = tid >> 6, lane = tid & 63;
  const int lo = lane & 15, hi = lane >> 4;
  const int m0 = blockIdx.y * BM, n0 = blockIdx.x * BN;
  const int wr = wid >> 1, wc = wid & 1;
  f32x4 acc[MR][NR] = {};

  const int nkt = K >> 6;
  for (int kt = 0; kt < nkt; ++kt) {
    __syncthreads();
    #pragma unroll
    for (int u = tid; u < BM * 8; u += 256) {
      int row = u >> 3, ch = u & 7, chs = ch ^ (row & 7);
      const unsigned short* ga = A + (size_t)(m0 + row) * K + kt * 64 + chs * 8;
      __builtin_amdgcn_global_load_lds((const __attribute__((address_space(1))) void*)ga,
                                       (__attribute__((address_space(3))) void*)(As + u * 8), 16, 0, 0);
    }
    #pragma unroll
    for (int u = tid; u < BN * 8; u += 256) {
      int row = u >> 3, ch = u & 7, chs = ch ^ (row & 7);
      const unsigned short* gb = Bt + (size_t)(n0 + row) * K + kt * 64 + chs * 8;
      __builtin_amdgcn_global_load_lds((const __attribute__((address_space(1))) void*)gb,
                                       (__attribute__((address_space(3))) void*)(Bs + u * 8), 16, 0, 0);
    }
    __syncthreads();
    #pragma unroll
    for (int ks = 0; ks < 2; ++ks) {
      const int chs = (ks * 4 + hi) ^ (lo & 7);
      bf16x8 a[MR], b[NR];
      #pragma unroll
      for (int m = 0; m < MR; ++m) {
        int row = wr * (BM / 2) + m * 16 + lo;
        a[m] = *(const bf16x8*)(As + row * 64 + chs * 8);
      }
      #pragma unroll
      for (int n = 0; n < NR; ++n) {
        int row = wc * (BN / 2) + n * 16 + lo;
        b[n] = *(const bf16x8*)(Bs + row * 64 + chs * 8);
      }
      #pragma unroll
      for (int m = 0; m < MR; ++m)
        #pragma unroll
        for (int n = 0; n < NR; ++n)
          acc[m][n] = __builtin_amdgcn_mfma_f32_16x16x32_bf16(a[m], b[n], acc[m][n], 0, 0, 0);
    }
  }

  if (MODE == 0) {
    const int cr = hi * 4;
    #pragma unroll
    for (int m = 0; m < MR; ++m)
      #pragma unroll
      for (int n = 0; n < NR; ++n) {
        int col = n0 + wc * (BN / 2) + n * 16 + lo;
        int rowb = m0 + wr * (BM / 2) + m * 16 + cr;
        #pragma unroll
        for (int r = 0; r < 4; ++r)
          C[(size_t)(rowb + r) * N + col] = acc[m][n][r];
      }
  } else {
    const int col0 = n0 + wc * (BN / 2);
    const int pos = posp[0];
    if (col0 < 2048) {            // ---- Q + RoPE ----
      const int h = col0 >> 6;
      #pragma unroll
      for (int m = 0; m < MR; ++m)
        #pragma unroll
        for (int r = 0; r < 4; ++r) {
          int row = m0 + wr * (BM / 2) + m * 16 + hi * 4 + r;
          int s = row & (S_ - 1), b = row >> 10;
          unsigned short* base = q_r + ((size_t)(b * H_ + h) * S_ + s) * HD_;
          #pragma unroll
          for (int np = 0; np < 2; ++np) {
            int i = np * 16 + lo;
            float t1 = acc[m][np][r], t2 = acc[m][np + 2][r];
            float c = cosT[(size_t)(pos + s) * 32 + i];
            float sn = sinT[(size_t)(pos + s) * 32 + i];
            base[i] = f2bf(t1 * c - t2 * sn);
            base[i + 32] = f2bf(t2 * c + t1 * sn);
          }
        }
    } else if (col0 < 2304) {     // ---- K + RoPE ----
      const int g = (col0 - 2048) >> 6;
      #pragma unroll
      for (int m = 0; m < MR; ++m)
        #pragma unroll
        for (int r = 0; r < 4; ++r) {
          int row = m0 + wr * (BM / 2) + m * 16 + hi * 4 + r;
          int s = row & (S_ - 1), b = row >> 10;
          unsigned short* base = k_r + ((size_t)(b * KV_ + g) * S_ + s) * HD_;
          #pragma unroll
          for (int np = 0; np < 2; ++np) {
            int i = np * 16 + lo;
            float t1 = acc[m][np][r], t2 = acc[m][np + 2][r];
            float c = cosT[(size_t)(pos + s) * 32 + i];
            float sn = sinT[(size_t)(pos + s) * 32 + i];
            base[i] = f2bf(t1 * c - t2 * sn);
            base[i + 32] = f2bf(t2 * c + t1 * sn);
          }
        }
    } else {                      // ---- V -> (B,KV,HD,S) transposed bf16 ----
      const int g = (col0 - 2304) >> 6;
      #pragma unroll
      for (int m = 0; m < MR; ++m) {
        int row0 = m0 + wr * (BM / 2) + m * 16 + hi * 4;
        int s0 = row0 & (S_ - 1), b = row0 >> 10;
        #pragma unroll
        for (int n = 0; n < NR; ++n) {
          int d = n * 16 + lo;
          ushort4 o;
          o.x = f2bf(acc[m][n][0]);
          o.y = f2bf(acc[m][n][1]);
          o.z = f2bf(acc[m][n][2]);
          o.w = f2bf(acc[m][n][3]);
          *(ushort4*)(v_t + ((size_t)(b * KV_ + g) * HD_ + d) * S_ + s0) = o;
        }
      }
    }
  }
}

// ---------------- MFMA flash attention: paired q-tiles + double-buffered K/V ----------------
// grid (S/128, H, B); block handles q-tiles qt=blockIdx.x and (S/64-1)-blockIdx.x
// -> uniform 17 chunks/block. 4 waves x 16 q-rows per tile. KV chunk 64, dbuf LDS.
__global__ __launch_bounds__(256) void k_attn(const unsigned short* __restrict__ qr,
                                              const unsigned short* __restrict__ kr,
                                              const unsigned short* __restrict__ vt,
                                              unsigned short* __restrict__ ao) {
  __shared__ alignas(16) unsigned short k_lds[2][64 * 64];
  __shared__ alignas(16) unsigned short v_lds[2][64 * 64];
  const int tid = threadIdx.x;
  const int wid = tid >> 6, lane = tid & 63;
  const int lo = lane & 15, hi = lane >> 4;
  const int b = blockIdx.z, h = blockIdx.y, g = h >> 3;
  const float kscale = 0.125f;           // 1/sqrt(64)

  const unsigned short* kbase = kr + (size_t)(b * KV_ + g) * S_ * HD_;
  const unsigned short* vbase = vt + (size_t)(b * KV_ + g) * HD_ * S_;
  int buf = 0;

  auto stage = [&](int c, int bi) {
    const int j0 = c * 64;
    #pragma unroll
    for (int i = 0; i < 2; ++i) {
      int u = i * 256 + tid;             // 16B unit, 0..511
      int r = u >> 3, ch = u & 7;
      int chs = ch ^ (r & 7);
      const unsigned short* gk = kbase + (size_t)(j0 + r) * HD_ + chs * 8;
      __builtin_amdgcn_global_load_lds((const __attribute__((address_space(1))) void*)gk,
                                       (__attribute__((address_space(3))) void*)(k_lds[bi] + u * 8), 16, 0, 0);
      const unsigned short* gv = vbase + (size_t)r * S_ + j0 + chs * 8;
      __builtin_amdgcn_global_load_lds((const __attribute__((address_space(1))) void*)gv,
                                       (__attribute__((address_space(3))) void*)(v_lds[bi] + u * 8), 16, 0, 0);
    }
  };

  auto processTile = [&](int qt) {
    const int q = qt * 64 + wid * 16 + lo;     // this lane's q row
    const unsigned short* qrow = qr + ((size_t)(b * H_ + h) * S_ + q) * HD_;
    bf16x8 qf[2];
    qf[0] = *(const bf16x8*)(qrow + hi * 8);
    qf[1] = *(const bf16x8*)(qrow + 32 + hi * 8);

    f32x4 oacc[4] = {};
    float mrun = -1e30f, lrun = 0.f;

    stage(0, buf);
    __syncthreads();

    for (int c = 0; c <= qt; ++c) {
      if (c < qt) stage(c + 1, buf ^ 1);  // prefetch next chunk (async, in flight during compute)
      const int j0 = c * 64;
      const unsigned short* kl = k_lds[buf];
      const unsigned short* vl = v_lds[buf];

      // S^T = K · Q^T
      f32x4 st[4];
      #pragma unroll
      for (int jt = 0; jt < 4; ++jt) st[jt] = (f32x4){0.f, 0.f, 0.f, 0.f};
      __builtin_amdgcn_s_setprio(1);
      #pragma unroll
      for (int ks = 0; ks < 2; ++ks)
        #pragma unroll
        for (int jt = 0; jt < 4; ++jt) {
          int row = jt * 16 + lo;
          int chs = (ks * 4 + hi) ^ (lo & 7);
          bf16x8 kf = *(const bf16x8*)(kl + row * 64 + chs * 8);
          st[jt] = __builtin_amdgcn_mfma_f32_16x16x32_bf16(kf, qf[ks], st[jt], 0, 0, 0);
        }
      __builtin_amdgcn_s_setprio(0);

      const bool diag = (c == qt);
      float pmax = -1e30f;
      #pragma unroll
      for (int jt = 0; jt < 4; ++jt)
        #pragma unroll
        for (int rr = 0; rr < 4; ++rr) {
          float sc = st[jt][rr] * kscale;
          if (diag && (j0 + jt * 16 + hi * 4 + rr > q)) sc = -1e30f;
          st[jt][rr] = sc;
          pmax = fmaxf(pmax, sc);
        }
      pmax = fmaxf(pmax, __shfl_xor(pmax, 16, 64));
      pmax = fmaxf(pmax, __shfl_xor(pmax, 32, 64));
      float mn = fmaxf(mrun, pmax);
      float scale = __expf(mrun - mn);
      float ps = 0.f;
      #pragma unroll
      for (int jt = 0; jt < 4; ++jt)
        #pragma unroll
        for (int rr = 0; rr < 4; ++rr) {
          float e = __expf(st[jt][rr] - mn);
          st[jt][rr] = e;
          ps += e;
        }
      ps += __shfl_xor(ps, 16, 64);
      ps += __shfl_xor(ps, 32, 64);
      lrun = lrun * scale + ps;
      mrun = mn;
      #pragma unroll
      for (int dt = 0; dt < 4; ++dt)
        #pragma unroll
        for (int rr = 0; rr < 4; ++rr) oacc[dt][rr] *= scale;

      unsigned int pk[4][2];
      #pragma unroll
      for (int jt = 0; jt < 4; ++jt)
        #pragma unroll
        for (int cp = 0; cp < 2; ++cp)
          pk[jt][cp] = (unsigned int)f2bf(st[jt][2 * cp]) |
                       ((unsigned int)f2bf(st[jt][2 * cp + 1]) << 16);

      int s0l = ((hi & 1) << 5) + lo;
      int s1l = s0l + 16;
      bool hb = (hi & 2) != 0;
      bf16x8 pf[2];
      #pragma unroll
      for (int ks = 0; ks < 2; ++ks) {
        unsigned int a0 = __shfl((int)pk[2 * ks][0], s0l, 64);
        unsigned int b0 = __shfl((int)pk[2 * ks + 1][0], s0l, 64);
        unsigned int a1 = __shfl((int)pk[2 * ks][1], s0l, 64);
        unsigned int b1 = __shfl((int)pk[2 * ks + 1][1], s0l, 64);
        unsigned int a2 = __shfl((int)pk[2 * ks][0], s1l, 64);
        unsigned int b2 = __shfl((int)pk[2 * ks + 1][0], s1l, 64);
        unsigned int a3 = __shfl((int)pk[2 * ks][1], s1l, 64);
        unsigned int b3 = __shfl((int)pk[2 * ks + 1][1], s1l, 64);
        union { unsigned int u[4]; bf16x8 v; } cvt;
        cvt.u[0] = hb ? b0 : a0;
        cvt.u[1] = hb ? b1 : a1;
        cvt.u[2] = hb ? b2 : a2;
        cvt.u[3] = hb ? b3 : a3;
        pf[ks] = cvt.v;
      }

      __builtin_amdgcn_s_setprio(1);
      #pragma unroll
      for (int ks = 0; ks < 2; ++ks)
        #pragma unroll
        for (int dt = 0; dt < 4; ++dt) {
          int row = dt * 16 + lo;
          int chs = (ks * 4 + hi) ^ (lo & 7);
          bf16x8 vf = *(const bf16x8*)(vl + row * 64 + chs * 8);
          oacc[dt] = __builtin_amdgcn_mfma_f32_16x16x32_bf16(vf, pf[ks], oacc[dt], 0, 0, 0);
        }
      __builtin_amdgcn_s_setprio(0);

      __syncthreads();                     // drains vmcnt -> next buf staged; all done reading buf
      if (c < qt) buf ^= 1;
    }

    float inv = 1.f / lrun;
    #pragma unroll
    for (int dt = 0; dt < 4; ++dt) {
      ushort4 o;
      o.x = f2bf(oacc[dt][0] * inv);
      o.y = f2bf(oacc[dt][1] * inv);
      o.z = f2bf(oacc[dt][2] * inv);
      o.w = f2bf(oacc[dt][3] * inv);
      *(ushort4*)(ao + ((size_t)(b * S_ + q)) * (H_ * HD_) + h * HD_ + dt * 16 + hi * 4) = o;
    }
  };

  processTile(blockIdx.x);
  processTile((S_ / 64 - 1) - blockIdx.x);
}

extern "C" void kernel_launch(void* const* d_in, const int* in_sizes, int n_in,
                              void* d_out, int out_size, void* d_ws, size_t ws_size,
                              hipStream_t stream) {
  const float* x    = (const float*)d_in[0];
  const float* wq   = (const float*)d_in[1];
  const float* wk   = (const float*)d_in[2];
  const float* wv   = (const float*)d_in[3];
  const float* wo   = (const float*)d_in[4];
  const float* cosT = (const float*)d_in[5];
  const float* sinT = (const float*)d_in[6];
  const int*   posp = (const int*)d_in[8];
  float* out = (float*)d_out;

  char* ws = (char*)d_ws;
  size_t off = 0;
  auto alloc = [&](size_t bytes) {
    char* p = ws + off;
    off += (bytes + 255) & ~(size_t)255;
    return p;
  };
  unsigned short* xb  = (unsigned short*)alloc((size_t)B_ * S_ * D_ * 2);
  unsigned short* wft = (unsigned short*)alloc((size_t)NQKV * D_ * 2);
  unsigned short* wot = (unsigned short*)alloc((size_t)D_ * D_ * 2);
  unsigned short* q_r = (unsigned short*)alloc((size_t)B_ * H_ * S_ * HD_ * 2);
  unsigned short* k_r = (unsigned short*)alloc((size_t)B_ * KV_ * S_ * HD_ * 2);
  unsigned short* v_t = (unsigned short*)alloc((size_t)B_ * KV_ * HD_ * S_ * 2);
  unsigned short* ao  = (unsigned short*)alloc((size_t)B_ * S_ * H_ * HD_ * 2);
  if (off > ws_size) return;

  k_convert<<<(B_ * S_ * D_ / 4 + 255) / 256, 256, 0, stream>>>(x, xb, B_ * S_ * D_ / 4);
  k_transpose<<<dim3(D_ / 32, D_ / 32), 256, 0, stream>>>(wq, wft, D_, D_, 0, D_);
  k_transpose<<<dim3((KV_ * HD_) / 32, D_ / 32), 256, 0, stream>>>(wk, wft, D_, KV_ * HD_, 2048, D_);
  k_transpose<<<dim3((KV_ * HD_) / 32, D_ / 32), 256, 0, stream>>>(wv, wft, D_, KV_ * HD_, 2304, D_);
  k_transpose<<<dim3(D_ / 32, D_ / 32), 256, 0, stream>>>(wo, wot, D_, D_, 0, D_);

  // QKV GEMM with fused RoPE / V-transpose epilogue: 64x128 tiles -> 640 blocks
  k_gemm<64, 128, 1><<<dim3(NQKV / 128, (B_ * S_) / 64), 256, 0, stream>>>(
      xb, wft, nullptr, cosT, sinT, posp, q_r, k_r, v_t, B_ * S_, NQKV, D_);

  // paired causal tiles: uniform 17 chunks/block
  k_attn<<<dim3(S_ / 128, H_, B_), 256, 0, stream>>>(q_r, k_r, v_t, ao);

  // Output GEMM: 64x128 tiles -> 512 blocks
  k_gemm<64, 128, 0><<<dim3(D_ / 128, (B_ * S_) / 64), 256, 0, stream>>>(
      ao, wot, out, nullptr, nullptr, nullptr, nullptr, nullptr, nullptr, B_ * S_, D_, D_);
}

// Round 6
// 114.572 us; speedup vs baseline: 7.9090x; 1.0190x over previous
//
#include <hip/hip_runtime.h>

#define B_ 2
#define S_ 1024
#define D_ 2048
#define H_ 32
#define KV_ 4
#define HD_ 64
#define NQKV 2560  // H*HD + KV*HD + KV*HD
#define KVB 64     // attention KV chunk

typedef __attribute__((ext_vector_type(8))) short bf16x8;
typedef __attribute__((ext_vector_type(4))) float f32x4;
typedef __attribute__((ext_vector_type(16))) float f32x16;

__device__ __forceinline__ unsigned short f2bf(float f) {
  unsigned int u = __float_as_uint(f);
  u = (u + 0x7fffu + ((u >> 16) & 1u)) >> 16;   // RNE
  return (unsigned short)u;
}

#define GLOAD_LDS(gp, lp) \
  __builtin_amdgcn_global_load_lds((const __attribute__((address_space(1))) void*)(gp), \
                                   (__attribute__((address_space(3))) void*)(lp), 16, 0, 0)

// ---------------- elementwise f32 -> bf16 ----------------
__global__ __launch_bounds__(256) void k_convert(const float* __restrict__ src,
                                                 unsigned short* __restrict__ dst, int n4) {
  int i = blockIdx.x * 256 + threadIdx.x;
  if (i >= n4) return;
  float4 v = ((const float4*)src)[i];
  ushort4 o;
  o.x = f2bf(v.x); o.y = f2bf(v.y); o.z = f2bf(v.z); o.w = f2bf(v.w);
  ((ushort4*)dst)[i] = o;
}

// ---------------- merged weight transposes: f32 (K x N) -> bf16 (N x K) ----------------
__global__ __launch_bounds__(256) void k_transpose4(const float* __restrict__ wq,
                                                    const float* __restrict__ wk,
                                                    const float* __restrict__ wv,
                                                    const float* __restrict__ wo,
                                                    unsigned short* __restrict__ wft,
                                                    unsigned short* __restrict__ wot) {
  __shared__ float tile[32][33];
  const int z = blockIdx.z;
  const float* src;
  unsigned short* dst;
  int N, roff;
  if (z == 0)      { src = wq; dst = wft; N = 2048; roff = 0; }
  else if (z == 1) { src = wk; dst = wft; N = 256;  roff = 2048; }
  else if (z == 2) { src = wv; dst = wft; N = 256;  roff = 2304; }
  else             { src = wo; dst = wot; N = 2048; roff = 0; }
  int n0 = blockIdx.x * 32, k0 = blockIdx.y * 32;
  if (n0 >= N) return;
  int tx = threadIdx.x & 31, ty = threadIdx.x >> 5;
  #pragma unroll
  for (int i = 0; i < 4; ++i)
    tile[ty + 8 * i][tx] = src[(size_t)(k0 + ty + 8 * i) * N + (n0 + tx)];
  __syncthreads();
  #pragma unroll
  for (int i = 0; i < 4; ++i)
    dst[(size_t)(roff + n0 + ty + 8 * i) * D_ + (k0 + tx)] = f2bf(tile[tx][ty + 8 * i]);
}

// ---------------- GEMM: C[M][N] = A[M][K] * Bt[N][K]^T, bf16 in ----------------
// MODE 0: plain f32 C write. MODE 1: fused QKV epilogue (RoPE q/k + q*0.125, V transpose).
template <int BM, int BN, int MODE>
__global__ __launch_bounds__(256) void k_gemm(const unsigned short* __restrict__ A,
                                              const unsigned short* __restrict__ Bt,
                                              float* __restrict__ C,
                                              const float* __restrict__ cosT,
                                              const float* __restrict__ sinT,
                                              const int* __restrict__ posp,
                                              unsigned short* __restrict__ q_r,
                                              unsigned short* __restrict__ k_r,
                                              unsigned short* __restrict__ v_t,
                                              int M, int N, int K) {
  constexpr int MR = BM / 32;
  constexpr int NR = BN / 32;
  __shared__ alignas(16) unsigned short As[BM * 64];
  __shared__ alignas(16) unsigned short Bs[BN * 64];
  const int tid = threadIdx.x;
  const int wid = tid >> 6, lane = tid & 63;
  const int lo = lane & 15, hi = lane >> 4;
  const int m0 = blockIdx.y * BM, n0 = blockIdx.x * BN;
  const int wr = wid >> 1, wc = wid & 1;
  f32x4 acc[MR][NR] = {};

  const int nkt = K >> 6;
  for (int kt = 0; kt < nkt; ++kt) {
    __syncthreads();
    #pragma unroll
    for (int u = tid; u < BM * 8; u += 256) {
      int row = u >> 3, ch = u & 7, chs = ch ^ (row & 7);
      GLOAD_LDS(A + (size_t)(m0 + row) * K + kt * 64 + chs * 8, As + u * 8);
    }
    #pragma unroll
    for (int u = tid; u < BN * 8; u += 256) {
      int row = u >> 3, ch = u & 7, chs = ch ^ (row & 7);
      GLOAD_LDS(Bt + (size_t)(n0 + row) * K + kt * 64 + chs * 8, Bs + u * 8);
    }
    __syncthreads();
    #pragma unroll
    for (int ks = 0; ks < 2; ++ks) {
      const int chs = (ks * 4 + hi) ^ (lo & 7);
      bf16x8 a[MR], b[NR];
      #pragma unroll
      for (int m = 0; m < MR; ++m) {
        int row = wr * (BM / 2) + m * 16 + lo;
        a[m] = *(const bf16x8*)(As + row * 64 + chs * 8);
      }
      #pragma unroll
      for (int n = 0; n < NR; ++n) {
        int row = wc * (BN / 2) + n * 16 + lo;
        b[n] = *(const bf16x8*)(Bs + row * 64 + chs * 8);
      }
      #pragma unroll
      for (int m = 0; m < MR; ++m)
        #pragma unroll
        for (int n = 0; n < NR; ++n)
          acc[m][n] = __builtin_amdgcn_mfma_f32_16x16x32_bf16(a[m], b[n], acc[m][n], 0, 0, 0);
    }
  }

  if (MODE == 0) {
    const int cr = hi * 4;
    #pragma unroll
    for (int m = 0; m < MR; ++m)
      #pragma unroll
      for (int n = 0; n < NR; ++n) {
        int col = n0 + wc * (BN / 2) + n * 16 + lo;
        int rowb = m0 + wr * (BM / 2) + m * 16 + cr;
        #pragma unroll
        for (int r = 0; r < 4; ++r)
          C[(size_t)(rowb + r) * N + col] = acc[m][n][r];
      }
  } else {
    const int col0 = n0 + wc * (BN / 2);
    const int pos = posp[0];
    if (col0 < 2048) {            // ---- Q + RoPE, pre-scaled by 1/sqrt(HD) ----
      const int h = col0 >> 6;
      #pragma unroll
      for (int m = 0; m < MR; ++m)
        #pragma unroll
        for (int r = 0; r < 4; ++r) {
          int row = m0 + wr * (BM / 2) + m * 16 + hi * 4 + r;
          int s = row & (S_ - 1), b = row >> 10;
          unsigned short* base = q_r + ((size_t)(b * H_ + h) * S_ + s) * HD_;
          #pragma unroll
          for (int np = 0; np < 2; ++np) {
            int i = np * 16 + lo;
            float t1 = acc[m][np][r], t2 = acc[m][np + 2][r];
            float c = cosT[(size_t)(pos + s) * 32 + i];
            float sn = sinT[(size_t)(pos + s) * 32 + i];
            base[i] = f2bf((t1 * c - t2 * sn) * 0.125f);
            base[i + 32] = f2bf((t2 * c + t1 * sn) * 0.125f);
          }
        }
    } else if (col0 < 2304) {     // ---- K + RoPE ----
      const int g = (col0 - 2048) >> 6;
      #pragma unroll
      for (int m = 0; m < MR; ++m)
        #pragma unroll
        for (int r = 0; r < 4; ++r) {
          int row = m0 + wr * (BM / 2) + m * 16 + hi * 4 + r;
          int s = row & (S_ - 1), b = row >> 10;
          unsigned short* base = k_r + ((size_t)(b * KV_ + g) * S_ + s) * HD_;
          #pragma unroll
          for (int np = 0; np < 2; ++np) {
            int i = np * 16 + lo;
            float t1 = acc[m][np][r], t2 = acc[m][np + 2][r];
            float c = cosT[(size_t)(pos + s) * 32 + i];
            float sn = sinT[(size_t)(pos + s) * 32 + i];
            base[i] = f2bf(t1 * c - t2 * sn);
            base[i + 32] = f2bf(t2 * c + t1 * sn);
          }
        }
    } else {                      // ---- V -> (B,KV,HD,S) transposed bf16 ----
      const int g = (col0 - 2304) >> 6;
      #pragma unroll
      for (int m = 0; m < MR; ++m) {
        int row0 = m0 + wr * (BM / 2) + m * 16 + hi * 4;
        int s0 = row0 & (S_ - 1), b = row0 >> 10;
        #pragma unroll
        for (int n = 0; n < NR; ++n) {
          int d = n * 16 + lo;
          ushort4 o;
          o.x = f2bf(acc[m][n][0]);
          o.y = f2bf(acc[m][n][1]);
          o.z = f2bf(acc[m][n][2]);
          o.w = f2bf(acc[m][n][3]);
          *(ushort4*)(v_t + ((size_t)(b * KV_ + g) * HD_ + d) * S_ + s0) = o;
        }
      }
    }
  }
}

// ---------------- MFMA flash attention, 32x32 swapped-QK^T, in-register softmax ----------
// grid flat 512; LPT remap: fid<256 -> qt=i (light), fid>=256 -> qt=7-i (heavy).
// Block: 4 waves x 32 q-rows = 128 q. Lane l & l^32 share q=l&31 and split j/d ranges.
__global__ __launch_bounds__(256) void k_attn(const unsigned short* __restrict__ qr,
                                              const unsigned short* __restrict__ kr,
                                              const unsigned short* __restrict__ vt,
                                              unsigned short* __restrict__ ao) {
  __shared__ alignas(16) unsigned short k_lds[2][KVB * HD_];   // [j][d], 16B-chunk XOR-swz
  __shared__ alignas(16) unsigned short v_lds[2][HD_ * KVB];   // [d][j], 16B-chunk XOR-swz
  const int tid = threadIdx.x;
  const int wid = tid >> 6, lane = tid & 63;
  const int l31 = lane & 31, hi5 = lane >> 5;

  const int fid = blockIdx.x + 8 * blockIdx.y + 256 * blockIdx.z;  // grid (8,32,2)
  const int half = fid >> 8, u0 = fid & 255;
  const int i4 = u0 >> 6, hb = u0 & 63;
  const int qt = half ? 7 - i4 : i4;
  const int h = hb >> 1, b = hb & 1, g = h >> 3;

  const int q_abs = qt * 128 + wid * 32 + l31;
  const int nch = 2 * qt + 2;

  // Q B-fragments (col=q=l31, k=hi5*8+idx per 16-dim step); kscale pre-folded
  const unsigned short* qrow = qr + ((size_t)(b * H_ + h) * S_ + q_abs) * HD_;
  bf16x8 qf[4];
  #pragma unroll
  for (int ks = 0; ks < 4; ++ks)
    qf[ks] = *(const bf16x8*)(qrow + ks * 16 + hi5 * 8);

  const unsigned short* kbase = kr + (size_t)(b * KV_ + g) * S_ * HD_;
  const unsigned short* vbase = vt + (size_t)(b * KV_ + g) * HD_ * S_;

  f32x16 oacc[2] = {};   // O^T: col q=l31, row d=(r&3)+8*(r>>2)+4*hi5+32*dt
  float mrun = -1e30f, ls = 0.f;
  int buf = 0;

  auto stage = [&](int c, int bi) {
    const int j0 = c * KVB;
    #pragma unroll
    for (int ii = 0; ii < 2; ++ii) {       // K: 64 j-rows x 8 chunks
      int uu = ii * 256 + tid;
      int r = uu >> 3, ch = uu & 7, chs = ch ^ (r & 7);
      GLOAD_LDS(kbase + (size_t)(j0 + r) * HD_ + chs * 8, k_lds[bi] + uu * 8);
    }
    #pragma unroll
    for (int ii = 0; ii < 2; ++ii) {       // V: 64 d-rows x 8 chunks
      int uu = ii * 256 + tid;
      int d = uu >> 3, ch = uu & 7, chs = ch ^ (d & 7);
      GLOAD_LDS(vbase + (size_t)d * S_ + j0 + chs * 8, v_lds[bi] + uu * 8);
    }
  };

  stage(0, 0);
  __syncthreads();

  for (int c = 0; c < nch; ++c) {
    if (c + 1 < nch) stage(c + 1, buf ^ 1);
    const unsigned short* kl = k_lds[buf];
    const unsigned short* vl = v_lds[buf];
    const int j0 = c * KVB;

    // S^T tiles (32j x 32q): A = K rows, B = Q
    f32x16 st[2] = {};
    __builtin_amdgcn_s_setprio(1);
    #pragma unroll
    for (int ks = 0; ks < 4; ++ks) {
      const int chs = ((ks * 2 + hi5) ^ (l31 & 7)) * 8;
      #pragma unroll
      for (int jt = 0; jt < 2; ++jt) {
        bf16x8 kf = *(const bf16x8*)(kl + (jt * 32 + l31) * HD_ + chs);
        st[jt] = __builtin_amdgcn_mfma_f32_32x32x16_bf16(kf, qf[ks], st[jt], 0, 0, 0);
      }
    }
    __builtin_amdgcn_s_setprio(0);

    // causal mask (last two chunks = diagonal q-tile) + row max
    float pmax = -1e30f;
    if (c >= nch - 2) {
      #pragma unroll
      for (int jt = 0; jt < 2; ++jt)
        #pragma unroll
        for (int r = 0; r < 16; ++r) {
          int j_abs = j0 + jt * 32 + (r & 3) + 8 * (r >> 2) + 4 * hi5;
          if (j_abs > q_abs) st[jt][r] = -1e30f;
          pmax = fmaxf(pmax, st[jt][r]);
        }
    } else {
      #pragma unroll
      for (int jt = 0; jt < 2; ++jt)
        #pragma unroll
        for (int r = 0; r < 16; ++r) pmax = fmaxf(pmax, st[jt][r]);
    }
    pmax = fmaxf(pmax, __shfl_xor(pmax, 32, 64));   // lane pair shares q
    float mn = fmaxf(mrun, pmax);
    float scale = __expf(mrun - mn);
    float lsl = 0.f;
    #pragma unroll
    for (int jt = 0; jt < 2; ++jt)
      #pragma unroll
      for (int r = 0; r < 16; ++r) {
        float e = __expf(st[jt][r] - mn);
        st[jt][r] = e;
        lsl += e;
      }
    ls = ls * scale + lsl;                          // per-lane partial; reduced at end
    mrun = mn;
    #pragma unroll
    for (int dt = 0; dt < 2; ++dt)
      #pragma unroll
      for (int r = 0; r < 16; ++r) oacc[dt][r] *= scale;

    // pack P to bf16 quads (pk[jt][quad] = rows {4q..4q+3} as 2 u32)
    unsigned int pk[2][4][2];
    #pragma unroll
    for (int jt = 0; jt < 2; ++jt)
      #pragma unroll
      for (int qd = 0; qd < 4; ++qd) {
        pk[jt][qd][0] = (unsigned int)f2bf(st[jt][qd * 4 + 0]) |
                        ((unsigned int)f2bf(st[jt][qd * 4 + 1]) << 16);
        pk[jt][qd][1] = (unsigned int)f2bf(st[jt][qd * 4 + 2]) |
                        ((unsigned int)f2bf(st[jt][qd * 4 + 3]) << 16);
      }

    // redistribute across lane^32 into PV B-fragments (k=j, col=q):
    // hi5=0 owns j rows {0-3,8-11,16-19,24-27}+32jt; hi5=1 owns {4-7,...,28-31}+32jt.
    // send the quads the partner needs; 8 shfl_xor(32) total.
    bf16x8 pf[4];
    #pragma unroll
    for (int jt = 0; jt < 2; ++jt) {
      unsigned int ex0a = hi5 ? pk[jt][0][0] : pk[jt][1][0];
      unsigned int ex0b = hi5 ? pk[jt][0][1] : pk[jt][1][1];
      unsigned int ex1a = hi5 ? pk[jt][2][0] : pk[jt][3][0];
      unsigned int ex1b = hi5 ? pk[jt][2][1] : pk[jt][3][1];
      unsigned int rA0 = (unsigned int)__shfl_xor((int)ex0a, 32, 64);
      unsigned int rA1 = (unsigned int)__shfl_xor((int)ex0b, 32, 64);
      unsigned int rB0 = (unsigned int)__shfl_xor((int)ex1a, 32, 64);
      unsigned int rB1 = (unsigned int)__shfl_xor((int)ex1b, 32, 64);
      union { unsigned int w[4]; bf16x8 v; } fe, fo;
      if (hi5) {
        fe.w[0] = rA0; fe.w[1] = rA1; fe.w[2] = pk[jt][1][0]; fe.w[3] = pk[jt][1][1];
        fo.w[0] = rB0; fo.w[1] = rB1; fo.w[2] = pk[jt][3][0]; fo.w[3] = pk[jt][3][1];
      } else {
        fe.w[0] = pk[jt][0][0]; fe.w[1] = pk[jt][0][1]; fe.w[2] = rA0; fe.w[3] = rA1;
        fo.w[0] = pk[jt][2][0]; fo.w[1] = pk[jt][2][1]; fo.w[2] = rB0; fo.w[3] = rB1;
      }
      pf[jt * 2 + 0] = fe.v;
      pf[jt * 2 + 1] = fo.v;
    }

    // O^T += Vt · P^T
    __builtin_amdgcn_s_setprio(1);
    #pragma unroll
    for (int ks = 0; ks < 4; ++ks) {
      const int chs = ((ks * 2 + hi5) ^ (l31 & 7)) * 8;
      #pragma unroll
      for (int dt = 0; dt < 2; ++dt) {
        bf16x8 vf = *(const bf16x8*)(vl + (dt * 32 + l31) * KVB + chs);
        oacc[dt] = __builtin_amdgcn_mfma_f32_32x32x16_bf16(vf, pf[ks], oacc[dt], 0, 0, 0);
      }
    }
    __builtin_amdgcn_s_setprio(0);

    __syncthreads();   // drains vmcnt: prefetch landed, all waves done with buf
    buf ^= 1;
  }

  float tot = ls + __shfl_xor(ls, 32, 64);
  float inv = 1.f / tot;
  unsigned short* orow = ao + (size_t)(b * S_ + q_abs) * (H_ * HD_) + h * HD_;
  #pragma unroll
  for (int dt = 0; dt < 2; ++dt)
    #pragma unroll
    for (int rg = 0; rg < 4; ++rg) {
      ushort4 o;
      o.x = f2bf(oacc[dt][rg * 4 + 0] * inv);
      o.y = f2bf(oacc[dt][rg * 4 + 1] * inv);
      o.z = f2bf(oacc[dt][rg * 4 + 2] * inv);
      o.w = f2bf(oacc[dt][rg * 4 + 3] * inv);
      *(ushort4*)(orow + dt * 32 + rg * 8 + hi5 * 4) = o;
    }
}

extern "C" void kernel_launch(void* const* d_in, const int* in_sizes, int n_in,
                              void* d_out, int out_size, void* d_ws, size_t ws_size,
                              hipStream_t stream) {
  const float* x    = (const float*)d_in[0];
  const float* wq   = (const float*)d_in[1];
  const float* wk   = (const float*)d_in[2];
  const float* wv   = (const float*)d_in[3];
  const float* wo   = (const float*)d_in[4];
  const float* cosT = (const float*)d_in[5];
  const float* sinT = (const float*)d_in[6];
  const int*   posp = (const int*)d_in[8];
  float* out = (float*)d_out;

  char* ws = (char*)d_ws;
  size_t off = 0;
  auto alloc = [&](size_t bytes) {
    char* p = ws + off;
    off += (bytes + 255) & ~(size_t)255;
    return p;
  };
  unsigned short* xb  = (unsigned short*)alloc((size_t)B_ * S_ * D_ * 2);
  unsigned short* wft = (unsigned short*)alloc((size_t)NQKV * D_ * 2);
  unsigned short* wot = (unsigned short*)alloc((size_t)D_ * D_ * 2);
  unsigned short* q_r = (unsigned short*)alloc((size_t)B_ * H_ * S_ * HD_ * 2);
  unsigned short* k_r = (unsigned short*)alloc((size_t)B_ * KV_ * S_ * HD_ * 2);
  unsigned short* v_t = (unsigned short*)alloc((size_t)B_ * KV_ * HD_ * S_ * 2);
  unsigned short* ao  = (unsigned short*)alloc((size_t)B_ * S_ * H_ * HD_ * 2);
  if (off > ws_size) return;

  k_convert<<<(B_ * S_ * D_ / 4 + 255) / 256, 256, 0, stream>>>(x, xb, B_ * S_ * D_ / 4);
  k_transpose4<<<dim3(D_ / 32, D_ / 32, 4), 256, 0, stream>>>(wq, wk, wv, wo, wft, wot);

  // QKV GEMM with fused RoPE (q pre-scaled) / V-transpose epilogue
  k_gemm<64, 128, 1><<<dim3(NQKV / 128, (B_ * S_) / 64), 256, 0, stream>>>(
      xb, wft, nullptr, cosT, sinT, posp, q_r, k_r, v_t, B_ * S_, NQKV, D_);

  // 32x32 swapped-QK^T attention, LPT-remapped grid
  k_attn<<<dim3(8, 32, 2), 256, 0, stream>>>(q_r, k_r, v_t, ao);

  // Output GEMM
  k_gemm<64, 128, 0><<<dim3(D_ / 128, (B_ * S_) / 64), 256, 0, stream>>>(
      ao, wot, out, nullptr, nullptr, nullptr, nullptr, nullptr, nullptr, B_ * S_, D_, D_);
}

// Round 8
// 110.449 us; speedup vs baseline: 8.2042x; 1.0373x over previous
//
#include <hip/hip_runtime.h>

#define B_ 2
#define S_ 1024
#define D_ 2048
#define H_ 32
#define KV_ 4
#define HD_ 64
#define NQKV 2560  // H*HD + KV*HD + KV*HD
#define KVB 64     // attention KV chunk

typedef __attribute__((ext_vector_type(8))) short bf16x8;
typedef __attribute__((ext_vector_type(4))) float f32x4;
typedef __attribute__((ext_vector_type(16))) float f32x16;

__device__ __forceinline__ unsigned short f2bf(float f) {
  unsigned int u = __float_as_uint(f);
  u = (u + 0x7fffu + ((u >> 16) & 1u)) >> 16;   // RNE
  return (unsigned short)u;
}
__device__ __forceinline__ unsigned int cvt_pk_bf16(float a, float b) {
  unsigned int r;
  asm("v_cvt_pk_bf16_f32 %0, %1, %2" : "=v"(r) : "v"(a), "v"(b));
  return r;
}
__device__ __forceinline__ float exp2f_fast(float x) {
  return __builtin_amdgcn_exp2f(x);   // bare v_exp_f32
}

#define GLOAD_LDS(gp, lp) \
  __builtin_amdgcn_global_load_lds((const __attribute__((address_space(1))) void*)(gp), \
                                   (__attribute__((address_space(3))) void*)(lp), 16, 0, 0)

// ---------------- elementwise f32 -> bf16 ----------------
__global__ __launch_bounds__(256) void k_convert(const float* __restrict__ src,
                                                 unsigned short* __restrict__ dst, int n4) {
  int i = blockIdx.x * 256 + threadIdx.x;
  if (i >= n4) return;
  float4 v = ((const float4*)src)[i];
  ushort4 o;
  o.x = f2bf(v.x); o.y = f2bf(v.y); o.z = f2bf(v.z); o.w = f2bf(v.w);
  ((ushort4*)dst)[i] = o;
}

// ---------------- merged weight transposes: f32 (K x N) -> bf16 (N x K) ----------------
__global__ __launch_bounds__(256) void k_transpose4(const float* __restrict__ wq,
                                                    const float* __restrict__ wk,
                                                    const float* __restrict__ wv,
                                                    const float* __restrict__ wo,
                                                    unsigned short* __restrict__ wft,
                                                    unsigned short* __restrict__ wot) {
  __shared__ float tile[32][33];
  const int z = blockIdx.z;
  const float* src;
  unsigned short* dst;
  int N, roff;
  if (z == 0)      { src = wq; dst = wft; N = 2048; roff = 0; }
  else if (z == 1) { src = wk; dst = wft; N = 256;  roff = 2048; }
  else if (z == 2) { src = wv; dst = wft; N = 256;  roff = 2304; }
  else             { src = wo; dst = wot; N = 2048; roff = 0; }
  int n0 = blockIdx.x * 32, k0 = blockIdx.y * 32;
  if (n0 >= N) return;
  int tx = threadIdx.x & 31, ty = threadIdx.x >> 5;
  #pragma unroll
  for (int i = 0; i < 4; ++i)
    tile[ty + 8 * i][tx] = src[(size_t)(k0 + ty + 8 * i) * N + (n0 + tx)];
  __syncthreads();
  #pragma unroll
  for (int i = 0; i < 4; ++i)
    dst[(size_t)(roff + n0 + ty + 8 * i) * D_ + (k0 + tx)] = f2bf(tile[tx][ty + 8 * i]);
}

// ---------------- GEMM: C[M][N] = A[M][K] * Bt[N][K]^T, bf16 in ----------------
// MODE 0: plain f32 C write. MODE 1: fused QKV epilogue (RoPE; q pre-scaled by
// log2(e)/sqrt(HD) for the log2-domain softmax; V transposed to (B,KV,HD,S)).
template <int BM, int BN, int MODE>
__global__ __launch_bounds__(256) void k_gemm(const unsigned short* __restrict__ A,
                                              const unsigned short* __restrict__ Bt,
                                              float* __restrict__ C,
                                              const float* __restrict__ cosT,
                                              const float* __restrict__ sinT,
                                              const int* __restrict__ posp,
                                              unsigned short* __restrict__ q_r,
                                              unsigned short* __restrict__ k_r,
                                              unsigned short* __restrict__ v_t,
                                              int M, int N, int K) {
  constexpr int MR = BM / 32;
  constexpr int NR = BN / 32;
  __shared__ alignas(16) unsigned short As[BM * 64];
  __shared__ alignas(16) unsigned short Bs[BN * 64];
  const int tid = threadIdx.x;
  const int wid = tid >> 6, lane = tid & 63;
  const int lo = lane & 15, hi = lane >> 4;
  const int m0 = blockIdx.y * BM, n0 = blockIdx.x * BN;
  const int wr = wid >> 1, wc = wid & 1;
  f32x4 acc[MR][NR] = {};

  const int nkt = K >> 6;
  for (int kt = 0; kt < nkt; ++kt) {
    __syncthreads();
    #pragma unroll
    for (int u = tid; u < BM * 8; u += 256) {
      int row = u >> 3, ch = u & 7, chs = ch ^ (row & 7);
      GLOAD_LDS(A + (size_t)(m0 + row) * K + kt * 64 + chs * 8, As + u * 8);
    }
    #pragma unroll
    for (int u = tid; u < BN * 8; u += 256) {
      int row = u >> 3, ch = u & 7, chs = ch ^ (row & 7);
      GLOAD_LDS(Bt + (size_t)(n0 + row) * K + kt * 64 + chs * 8, Bs + u * 8);
    }
    __syncthreads();
    #pragma unroll
    for (int ks = 0; ks < 2; ++ks) {
      const int chs = (ks * 4 + hi) ^ (lo & 7);
      bf16x8 a[MR], b[NR];
      #pragma unroll
      for (int m = 0; m < MR; ++m) {
        int row = wr * (BM / 2) + m * 16 + lo;
        a[m] = *(const bf16x8*)(As + row * 64 + chs * 8);
      }
      #pragma unroll
      for (int n = 0; n < NR; ++n) {
        int row = wc * (BN / 2) + n * 16 + lo;
        b[n] = *(const bf16x8*)(Bs + row * 64 + chs * 8);
      }
      #pragma unroll
      for (int m = 0; m < MR; ++m)
        #pragma unroll
        for (int n = 0; n < NR; ++n)
          acc[m][n] = __builtin_amdgcn_mfma_f32_16x16x32_bf16(a[m], b[n], acc[m][n], 0, 0, 0);
    }
  }

  if (MODE == 0) {
    const int cr = hi * 4;
    #pragma unroll
    for (int m = 0; m < MR; ++m)
      #pragma unroll
      for (int n = 0; n < NR; ++n) {
        int col = n0 + wc * (BN / 2) + n * 16 + lo;
        int rowb = m0 + wr * (BM / 2) + m * 16 + cr;
        #pragma unroll
        for (int r = 0; r < 4; ++r)
          C[(size_t)(rowb + r) * N + col] = acc[m][n][r];
      }
  } else {
    const int col0 = n0 + wc * (BN / 2);
    const int pos = posp[0];
    const float qsc = 0.125f * 1.44269504f;   // 1/sqrt(HD) * log2(e)
    if (col0 < 2048) {            // ---- Q + RoPE, pre-scaled ----
      const int h = col0 >> 6;
      #pragma unroll
      for (int m = 0; m < MR; ++m)
        #pragma unroll
        for (int r = 0; r < 4; ++r) {
          int row = m0 + wr * (BM / 2) + m * 16 + hi * 4 + r;
          int s = row & (S_ - 1), b = row >> 10;
          unsigned short* base = q_r + ((size_t)(b * H_ + h) * S_ + s) * HD_;
          #pragma unroll
          for (int np = 0; np < 2; ++np) {
            int i = np * 16 + lo;
            float t1 = acc[m][np][r], t2 = acc[m][np + 2][r];
            float c = cosT[(size_t)(pos + s) * 32 + i];
            float sn = sinT[(size_t)(pos + s) * 32 + i];
            base[i] = f2bf((t1 * c - t2 * sn) * qsc);
            base[i + 32] = f2bf((t2 * c + t1 * sn) * qsc);
          }
        }
    } else if (col0 < 2304) {     // ---- K + RoPE ----
      const int g = (col0 - 2048) >> 6;
      #pragma unroll
      for (int m = 0; m < MR; ++m)
        #pragma unroll
        for (int r = 0; r < 4; ++r) {
          int row = m0 + wr * (BM / 2) + m * 16 + hi * 4 + r;
          int s = row & (S_ - 1), b = row >> 10;
          unsigned short* base = k_r + ((size_t)(b * KV_ + g) * S_ + s) * HD_;
          #pragma unroll
          for (int np = 0; np < 2; ++np) {
            int i = np * 16 + lo;
            float t1 = acc[m][np][r], t2 = acc[m][np + 2][r];
            float c = cosT[(size_t)(pos + s) * 32 + i];
            float sn = sinT[(size_t)(pos + s) * 32 + i];
            base[i] = f2bf(t1 * c - t2 * sn);
            base[i + 32] = f2bf(t2 * c + t1 * sn);
          }
        }
    } else {                      // ---- V -> (B,KV,HD,S) transposed bf16 ----
      const int g = (col0 - 2304) >> 6;
      #pragma unroll
      for (int m = 0; m < MR; ++m) {
        int row0 = m0 + wr * (BM / 2) + m * 16 + hi * 4;
        int s0 = row0 & (S_ - 1), b = row0 >> 10;
        #pragma unroll
        for (int n = 0; n < NR; ++n) {
          int d = n * 16 + lo;
          ushort4 o;
          o.x = f2bf(acc[m][n][0]);
          o.y = f2bf(acc[m][n][1]);
          o.z = f2bf(acc[m][n][2]);
          o.w = f2bf(acc[m][n][3]);
          *(ushort4*)(v_t + ((size_t)(b * KV_ + g) * HD_ + d) * S_ + s0) = o;
        }
      }
    }
  }
}

// ---------------- MFMA flash attention, 32x32 swapped-QK^T, log2-domain softmax ------------
// grid (64 bh, 16 qt); heavy-first (qt = 15 - blockIdx.y). 2 waves x 32 q = 64 q/block.
// Lane l & l^32 share q=l&31 and split j/d ranges. nch = qt+1 chunks of 64.
__global__ __launch_bounds__(128) void k_attn(const unsigned short* __restrict__ qr,
                                              const unsigned short* __restrict__ kr,
                                              const unsigned short* __restrict__ vt,
                                              unsigned short* __restrict__ ao) {
  __shared__ alignas(16) unsigned short k_lds[2 * KVB * HD_];   // [buf][j][d], chunk-XOR-swz
  __shared__ alignas(16) unsigned short v_lds[2 * HD_ * KVB];   // [buf][d][j], chunk-XOR-swz
  const int tid = threadIdx.x;
  const int wid = tid >> 6, lane = tid & 63;
  const int l31 = lane & 31, hi5 = lane >> 5;
  const int bh = blockIdx.x;
  const int h = bh >> 1, b = bh & 1, g = h >> 3;
  const int qt = 15 - (int)blockIdx.y;            // heavy-first dispatch
  const int nch = qt + 1;
  const int q_abs = qt * 64 + wid * 32 + l31;

  // Q B-fragments (col=q=l31, k = ks*16 + hi5*8 ..); scale pre-folded in GEMM epilogue
  const unsigned short* qrow = qr + ((size_t)(b * H_ + h) * S_ + q_abs) * HD_;
  bf16x8 qf[4];
  #pragma unroll
  for (int ks = 0; ks < 4; ++ks)
    qf[ks] = *(const bf16x8*)(qrow + ks * 16 + hi5 * 8);

  const unsigned short* kbase = kr + (size_t)(b * KV_ + g) * S_ * HD_;
  const unsigned short* vbase = vt + (size_t)(b * KV_ + g) * HD_ * S_;

  // hoisted per-thread staging sources + LDS dests (chunk delta is a constant add)
  const unsigned short* kg[4];
  const unsigned short* vg[4];
  int ldo[4];
  #pragma unroll
  for (int ii = 0; ii < 4; ++ii) {
    int uu = ii * 128 + tid;               // 16B unit, 0..511
    int r = uu >> 3, ch = uu & 7, chs = ch ^ (r & 7);
    kg[ii] = kbase + r * HD_ + chs * 8;
    vg[ii] = vbase + (size_t)r * S_ + chs * 8;
    ldo[ii] = uu * 8;
  }
  int chs8[4];
  #pragma unroll
  for (int ks = 0; ks < 4; ++ks) chs8[ks] = ((ks * 2 + hi5) ^ (l31 & 7)) * 8;
  const int krow = l31 * 64;

  f32x16 oacc[2] = {};   // O^T: col q=l31, row d=(r&3)+8*(r>>2)+4*hi5+32*dt
  float mrun = -1e30f, ls = 0.f;
  int buf = 0;

  auto stage = [&](int c, int bi) {
    #pragma unroll
    for (int ii = 0; ii < 4; ++ii)
      GLOAD_LDS(kg[ii] + (size_t)c * (KVB * HD_), k_lds + bi * 4096 + ldo[ii]);
    #pragma unroll
    for (int ii = 0; ii < 4; ++ii)
      GLOAD_LDS(vg[ii] + (size_t)c * KVB, v_lds + bi * 4096 + ldo[ii]);
  };

  stage(0, 0);
  __syncthreads();

  for (int c = 0; c < nch; ++c) {
    if (c + 1 < nch) stage(c + 1, buf ^ 1);
    const unsigned short* kl = k_lds + buf * 4096;
    const unsigned short* vl = v_lds + buf * 4096;
    const int j0 = c * KVB;

    // S^T tiles (32j x 32q): A = K rows, B = Q
    f32x16 st[2] = {};
    __builtin_amdgcn_s_setprio(1);
    #pragma unroll
    for (int ks = 0; ks < 4; ++ks)
      #pragma unroll
      for (int jt = 0; jt < 2; ++jt) {
        bf16x8 kf = *(const bf16x8*)(kl + jt * 2048 + krow + chs8[ks]);
        st[jt] = __builtin_amdgcn_mfma_f32_32x32x16_bf16(kf, qf[ks], st[jt], 0, 0, 0);
      }
    __builtin_amdgcn_s_setprio(0);

    // causal mask (diagonal chunk only) + row max
    float pmax = -1e30f;
    if (c == nch - 1) {
      #pragma unroll
      for (int jt = 0; jt < 2; ++jt)
        #pragma unroll
        for (int r = 0; r < 16; ++r) {
          int j_abs = j0 + jt * 32 + (r & 3) + 8 * (r >> 2) + 4 * hi5;
          if (j_abs > q_abs) st[jt][r] = -1e30f;
          pmax = fmaxf(pmax, st[jt][r]);
        }
    } else {
      #pragma unroll
      for (int jt = 0; jt < 2; ++jt)
        #pragma unroll
        for (int r = 0; r < 16; ++r) pmax = fmaxf(pmax, st[jt][r]);
    }
    pmax = fmaxf(pmax, __shfl_xor(pmax, 32, 64));   // lane pair shares q

    // defer-max: rescale only when some lane's max rose (wave-uniform branch)
    if (__any(pmax > mrun)) {
      float mn = fmaxf(mrun, pmax);
      float scale = exp2f_fast(mrun - mn);
      ls *= scale;
      #pragma unroll
      for (int dt = 0; dt < 2; ++dt)
        #pragma unroll
        for (int r = 0; r < 16; ++r) oacc[dt][r] *= scale;
      mrun = mn;
    }
    float ls0 = 0.f, ls1 = 0.f, ls2 = 0.f, ls3 = 0.f;
    #pragma unroll
    for (int jt = 0; jt < 2; ++jt)
      #pragma unroll
      for (int r = 0; r < 16; ++r) {
        float e = exp2f_fast(st[jt][r] - mrun);   // log2-domain: bare v_exp_f32
        st[jt][r] = e;
        if ((r & 3) == 0) ls0 += e; else if ((r & 3) == 1) ls1 += e;
        else if ((r & 3) == 2) ls2 += e; else ls3 += e;
      }
    ls += (ls0 + ls1) + (ls2 + ls3);

    // pack P to bf16 quads via v_cvt_pk_bf16_f32 (pk[jt][quad] = rows {4q..4q+3})
    unsigned int pk[2][4][2];
    #pragma unroll
    for (int jt = 0; jt < 2; ++jt)
      #pragma unroll
      for (int qd = 0; qd < 4; ++qd) {
        pk[jt][qd][0] = cvt_pk_bf16(st[jt][qd * 4 + 0], st[jt][qd * 4 + 1]);
        pk[jt][qd][1] = cvt_pk_bf16(st[jt][qd * 4 + 2], st[jt][qd * 4 + 3]);
      }

    // redistribute across lane^32 into PV B-fragments (k=j, col=q)
    bf16x8 pf[4];
    #pragma unroll
    for (int jt = 0; jt < 2; ++jt) {
      unsigned int ex0a = hi5 ? pk[jt][0][0] : pk[jt][1][0];
      unsigned int ex0b = hi5 ? pk[jt][0][1] : pk[jt][1][1];
      unsigned int ex1a = hi5 ? pk[jt][2][0] : pk[jt][3][0];
      unsigned int ex1b = hi5 ? pk[jt][2][1] : pk[jt][3][1];
      unsigned int rA0 = (unsigned int)__shfl_xor((int)ex0a, 32, 64);
      unsigned int rA1 = (unsigned int)__shfl_xor((int)ex0b, 32, 64);
      unsigned int rB0 = (unsigned int)__shfl_xor((int)ex1a, 32, 64);
      unsigned int rB1 = (unsigned int)__shfl_xor((int)ex1b, 32, 64);
      union { unsigned int w[4]; bf16x8 v; } fe, fo;
      if (hi5) {
        fe.w[0] = rA0; fe.w[1] = rA1; fe.w[2] = pk[jt][1][0]; fe.w[3] = pk[jt][1][1];
        fo.w[0] = rB0; fo.w[1] = rB1; fo.w[2] = pk[jt][3][0]; fo.w[3] = pk[jt][3][1];
      } else {
        fe.w[0] = pk[jt][0][0]; fe.w[1] = pk[jt][0][1]; fe.w[2] = rA0; fe.w[3] = rA1;
        fo.w[0] = pk[jt][2][0]; fo.w[1] = pk[jt][2][1]; fo.w[2] = rB0; fo.w[3] = rB1;
      }
      pf[jt * 2 + 0] = fe.v;
      pf[jt * 2 + 1] = fo.v;
    }

    // O^T += Vt · P^T
    __builtin_amdgcn_s_setprio(1);
    #pragma unroll
    for (int ks = 0; ks < 4; ++ks)
      #pragma unroll
      for (int dt = 0; dt < 2; ++dt) {
        bf16x8 vf = *(const bf16x8*)(vl + dt * 2048 + krow + chs8[ks]);
        oacc[dt] = __builtin_amdgcn_mfma_f32_32x32x16_bf16(vf, pf[ks], oacc[dt], 0, 0, 0);
      }
    __builtin_amdgcn_s_setprio(0);

    __syncthreads();   // prefetch landed; all waves done with buf
    buf ^= 1;
  }

  float tot = ls + __shfl_xor(ls, 32, 64);
  float inv = 1.f / tot;
  unsigned short* orow = ao + (size_t)(b * S_ + q_abs) * (H_ * HD_) + h * HD_;
  #pragma unroll
  for (int dt = 0; dt < 2; ++dt)
    #pragma unroll
    for (int rg = 0; rg < 4; ++rg) {
      uint2 w;
      w.x = cvt_pk_bf16(oacc[dt][rg * 4 + 0] * inv, oacc[dt][rg * 4 + 1] * inv);
      w.y = cvt_pk_bf16(oacc[dt][rg * 4 + 2] * inv, oacc[dt][rg * 4 + 3] * inv);
      *(uint2*)(orow + dt * 32 + rg * 8 + hi5 * 4) = w;
    }
}

extern "C" void kernel_launch(void* const* d_in, const int* in_sizes, int n_in,
                              void* d_out, int out_size, void* d_ws, size_t ws_size,
                              hipStream_t stream) {
  const float* x    = (const float*)d_in[0];
  const float* wq   = (const float*)d_in[1];
  const float* wk   = (const float*)d_in[2];
  const float* wv   = (const float*)d_in[3];
  const float* wo   = (const float*)d_in[4];
  const float* cosT = (const float*)d_in[5];
  const float* sinT = (const float*)d_in[6];
  const int*   posp = (const int*)d_in[8];
  float* out = (float*)d_out;

  char* ws = (char*)d_ws;
  size_t off = 0;
  auto alloc = [&](size_t bytes) {
    char* p = ws + off;
    off += (bytes + 255) & ~(size_t)255;
    return p;
  };
  unsigned short* xb  = (unsigned short*)alloc((size_t)B_ * S_ * D_ * 2);
  unsigned short* wft = (unsigned short*)alloc((size_t)NQKV * D_ * 2);
  unsigned short* wot = (unsigned short*)alloc((size_t)D_ * D_ * 2);
  unsigned short* q_r = (unsigned short*)alloc((size_t)B_ * H_ * S_ * HD_ * 2);
  unsigned short* k_r = (unsigned short*)alloc((size_t)B_ * KV_ * S_ * HD_ * 2);
  unsigned short* v_t = (unsigned short*)alloc((size_t)B_ * KV_ * HD_ * S_ * 2);
  unsigned short* ao  = (unsigned short*)alloc((size_t)B_ * S_ * H_ * HD_ * 2);
  if (off > ws_size) return;

  k_convert<<<(B_ * S_ * D_ / 4 + 255) / 256, 256, 0, stream>>>(x, xb, B_ * S_ * D_ / 4);
  k_transpose4<<<dim3(D_ / 32, D_ / 32, 4), 256, 0, stream>>>(wq, wk, wv, wo, wft, wot);

  // QKV GEMM with fused RoPE (q pre-scaled by log2e/8) / V-transpose epilogue
  k_gemm<64, 128, 1><<<dim3(NQKV / 128, (B_ * S_) / 64), 256, 0, stream>>>(
      xb, wft, nullptr, cosT, sinT, posp, q_r, k_r, v_t, B_ * S_, NQKV, D_);

  // 32x32 swapped-QK^T attention, heavy-first uniform blocks (2 waves, 64 q each)
  k_attn<<<dim3(64, 16), 128, 0, stream>>>(q_r, k_r, v_t, ao);

  // Output GEMM
  k_gemm<64, 128, 0><<<dim3(D_ / 128, (B_ * S_) / 64), 256, 0, stream>>>(
      ao, wot, out, nullptr, nullptr, nullptr, nullptr, nullptr, nullptr, B_ * S_, D_, D_);
}